// Round 3
// baseline (777.868 us; speedup 1.0000x reference)
//
#include <hip/hip_runtime.h>
#include <math.h>

// B=32 graphs, N=1024 nodes, D=128 in-dim, C=64 out-dim, K=16.
#define OUT_ELEMS 2097152   // 32768*64
#define EDGE_ELEMS 524288   // 32*1024*16
#define H64_BYTES (32768ull * 64ull * 8ull)  // 16 MiB f64 embeddings in ws

__device__ __forceinline__ unsigned int rotl32(unsigned int x, int r){
  return (x << r) | (x >> (32 - r));
}

// JAX *partitionable* threefry bits (default since jax 0.4.30), key (0,1):
// counter pair = (hi32(idx), lo32(idx)) = (0, e) for e < 2^32; 32-bit output
// is o0 ^ o1 of the 20-round threefry2x32.
__device__ __forceinline__ unsigned int tf_bits_part(unsigned int e){
  unsigned int x0 = 0u, x1 = e;
  const unsigned int ks1 = 1u;
  const unsigned int ks2 = 0x1BD11BDBu; // 0x1BD11BDA ^ 0 ^ 1
  // initial key injection: x0 += ks0(=0); x1 += ks1
  x1 += ks1;
#define TFR(r) { x0 += x1; x1 = rotl32(x1, r); x1 ^= x0; }
  TFR(13) TFR(15) TFR(26) TFR(6)
  x0 += ks1; x1 += ks2 + 1u;
  TFR(17) TFR(29) TFR(16) TFR(24)
  x0 += ks2; x1 += 0u + 2u;
  TFR(13) TFR(15) TFR(26) TFR(6)
  x0 += 0u;  x1 += ks1 + 3u;
  TFR(17) TFR(29) TFR(16) TFR(24)
  x0 += ks1; x1 += ks2 + 4u;
  TFR(13) TFR(15) TFR(26) TFR(6)
  x0 += ks2; x1 += 0u + 5u;
#undef TFR
  return x0 ^ x1;
}

// u built exactly like jax: f32 bit pattern (bits>>9)|0x3f800000 minus 1,
// clamped to f32 tiny; downstream logs in f64.
__device__ __forceinline__ double gumbel_z(unsigned int bits){
  float f = __uint_as_float(0x3f800000u | (bits >> 9)) - 1.0f;
  double u = (f > 0.0f) ? (double)f : 1.1754943508222875e-38;
  return -log(-log(u));
}

// out[i][c] = f32(sum_k x*W + b); h64 keeps the unrounded f64 value.
__global__ __launch_bounds__(256) void encoder_kernel(
    const float* __restrict__ x, const float* __restrict__ W,
    const float* __restrict__ b, float* __restrict__ out,
    double* __restrict__ h64, int write64){
  __shared__ float xs[512]; // 4 rows x 128
  const int tid = threadIdx.x;
  const size_t row0 = (size_t)blockIdx.x << 2;
  ((float2*)xs)[tid] = ((const float2*)(x + (row0 << 7)))[tid];
  __syncthreads();
  const int c = tid & 63, r = tid >> 6;
  double acc = (double)b[c];
  const float* xr = xs + (r << 7);
  #pragma unroll 16
  for (int k = 0; k < 128; ++k)
    acc += (double)xr[k] * (double)W[(k << 6) + c];
  const size_t idx = ((row0 + (size_t)r) << 6) + c;
  out[idx] = (float)acc;
  if (write64) h64[idx] = acc;
}

// One block = 4 rows (i0..i0+3) of graph gb. Full-f64 scores, then per-wave
// top-16 (value desc, index asc) matching lax.top_k semantics.
template<typename T>
__global__ __launch_bounds__(256) void edges_kernel(
    const T* __restrict__ h, const float* __restrict__ temp,
    float* __restrict__ rows_out, float* __restrict__ cols_out){
  __shared__ double hi[4][64];
  __shared__ double sv[4][1024];
  const int tid = threadIdx.x;
  const int gb = blockIdx.x >> 8;          // graph 0..31
  const int i0 = (blockIdx.x & 255) << 2;  // first local row
  const T* __restrict__ hbase = h + ((size_t)gb << 16); // gb*1024*64

  hi[tid >> 6][tid & 63] = (double)hbase[((size_t)i0 << 6) + tid];
  __syncthreads();

  const double Tmp = (double)temp[0];

  double acc[4][4];
  #pragma unroll
  for (int r = 0; r < 4; ++r)
    #pragma unroll
    for (int jj = 0; jj < 4; ++jj) acc[r][jj] = 0.0;

  #pragma unroll 1
  for (int jj = 0; jj < 4; ++jj){
    const T* __restrict__ hjr = hbase + (((size_t)(jj << 8) + tid) << 6);
    #pragma unroll 8
    for (int q = 0; q < 64; ++q){
      double bq = (double)hjr[q];
      #pragma unroll
      for (int r = 0; r < 4; ++r){
        double d = hi[r][q] - bq;
        acc[r][jj] = fma(d, d, acc[r][jj]);
      }
    }
  }

  #pragma unroll
  for (int r = 0; r < 4; ++r){
    #pragma unroll
    for (int jj = 0; jj < 4; ++jj){
      int j = (jj << 8) + tid;
      // flat row-major element index into [32,1024,1024]
      unsigned int e = ((unsigned int)gb << 20) |
                       ((unsigned int)(i0 + r) << 10) | (unsigned int)j;
      unsigned int bits = tf_bits_part(e);
      sv[r][j] = exp(-Tmp * acc[r][jj]) + gumbel_z(bits);
    }
  }
  __syncthreads();

  const int wave = tid >> 6, lane = tid & 63;
  double v[16];
  #pragma unroll
  for (int m = 0; m < 16; ++m) v[m] = sv[wave][(m << 6) + lane];

  const int grow = (gb << 10) + i0 + wave;
  float* rowp = rows_out + ((size_t)grow << 4);
  float* colp = cols_out + ((size_t)grow << 4);
  if (lane < 16) rowp[lane] = (float)grow;

  #pragma unroll 1
  for (int k = 0; k < 16; ++k){
    double bv = -1.0e308; int bj = 1 << 30;
    #pragma unroll
    for (int m = 0; m < 16; ++m){
      int j = (m << 6) + lane;
      bool better = (v[m] > bv) || (v[m] == bv && j < bj);
      if (better){ bv = v[m]; bj = j; }
    }
    #pragma unroll
    for (int off = 32; off; off >>= 1){
      double ov = __shfl_xor(bv, off, 64);
      int    oj = __shfl_xor(bj, off, 64);
      bool better = (ov > bv) || (ov == bv && oj < bj);
      if (better){ bv = ov; bj = oj; }
    }
    if ((bj & 63) == lane) v[bj >> 6] = -1.0e308;
    if (lane == 0) colp[k] = (float)((gb << 10) + bj);
  }
}

extern "C" void kernel_launch(void* const* d_in, const int* in_sizes, int n_in,
                              void* d_out, int out_size, void* d_ws, size_t ws_size,
                              hipStream_t stream){
  const float* x = (const float*)d_in[0];
  const float* W = (const float*)d_in[1];
  const float* b = (const float*)d_in[2];
  const float* T = (const float*)d_in[3];
  float* out      = (float*)d_out;
  float* rows_out = out + OUT_ELEMS;
  float* cols_out = rows_out + EDGE_ELEMS;

  double* h64 = (double*)d_ws;
  const int have_ws = (ws_size >= H64_BYTES) ? 1 : 0;

  encoder_kernel<<<8192, 256, 0, stream>>>(x, W, b, out, h64, have_ws);
  if (have_ws)
    edges_kernel<double><<<8192, 256, 0, stream>>>(h64, T, rows_out, cols_out);
  else
    edges_kernel<float><<<8192, 256, 0, stream>>>(out, T, rows_out, cols_out);
}

// Round 4
// 652.789 us; speedup vs baseline: 1.1916x; 1.1916x over previous
//
#include <hip/hip_runtime.h>
#include <math.h>

// B=32 graphs, N=1024 nodes, D=128 in-dim, C=64 out-dim, K=16.
#define OUT_ELEMS 2097152   // 32768*64
#define EDGE_ELEMS 524288   // 32*1024*16
#define H64_BYTES (32768ull * 64ull * 8ull)   // 16 MiB f64 embeddings
#define HT_BYTES  (32768ull * 64ull * 8ull)   // 16 MiB transposed f64
#define SQ_BYTES  (32768ull * 8ull)           // 256 KiB row norms
#define WS_FULL   (H64_BYTES + HT_BYTES + SQ_BYTES)

__device__ __forceinline__ unsigned int rotl32(unsigned int x, int r){
  return (x << r) | (x >> (32 - r));
}

// JAX partitionable threefry, key (0,1): counter = (0, e); out = o0 ^ o1.
__device__ __forceinline__ unsigned int tf_bits_part(unsigned int e){
  unsigned int x0 = 0u, x1 = e;
  const unsigned int ks1 = 1u;
  const unsigned int ks2 = 0x1BD11BDBu;
  x1 += ks1;
#define TFR(r) { x0 += x1; x1 = rotl32(x1, r); x1 ^= x0; }
  TFR(13) TFR(15) TFR(26) TFR(6)
  x0 += ks1; x1 += ks2 + 1u;
  TFR(17) TFR(29) TFR(16) TFR(24)
  x0 += ks2; x1 += 0u + 2u;
  TFR(13) TFR(15) TFR(26) TFR(6)
  x0 += 0u;  x1 += ks1 + 3u;
  TFR(17) TFR(29) TFR(16) TFR(24)
  x0 += ks1; x1 += ks2 + 4u;
  TFR(13) TFR(15) TFR(26) TFR(6)
  x0 += ks2; x1 += 0u + 5u;
#undef TFR
  return x0 ^ x1;
}

// fast e^x for x in [-740, ~1]; rel err ~6e-15. No edge handling needed.
__device__ __forceinline__ double fast_exp(double x){
  double fn = __builtin_rint(x * 1.4426950408889634);
  int n = (int)fn;
  double r = fma(fn, -0.6931471803691238, x);     // -ln2_hi
  r = fma(fn, -1.9082149292705877e-10, r);        // -ln2_lo
  double p = fma(r, 1.0/39916800.0, 1.0/3628800.0);
  p = fma(r, p, 1.0/362880.0); p = fma(r, p, 1.0/40320.0);
  p = fma(r, p, 1.0/5040.0);   p = fma(r, p, 1.0/720.0);
  p = fma(r, p, 1.0/120.0);    p = fma(r, p, 1.0/24.0);
  p = fma(r, p, 1.0/6.0);      p = fma(r, p, 0.5);
  p = fma(r, p, 1.0);          p = fma(r, p, 1.0);
  double scale = __longlong_as_double(((long long)(n + 1023)) << 52);
  return p * scale;
}

// fast ln(x) for normal positive x; rel err ~5e-11 (atanh form).
__device__ __forceinline__ double fast_log(double x){
  unsigned long long bx = (unsigned long long)__double_as_longlong(x);
  long long e = (long long)(bx >> 52) - 1023;
  double m = __longlong_as_double((long long)((bx & 0xFFFFFFFFFFFFFull) |
                                              0x3FF0000000000000ull));
  int big = m > 1.4142135623730951;
  m = big ? 0.5 * m : m;
  e += big;
  double t = m - 1.0;
  double s = t / (m + 1.0);
  double s2 = s * s;
  double p = fma(s2, 2.0/13.0, 2.0/11.0);
  p = fma(s2, p, 2.0/9.0); p = fma(s2, p, 2.0/7.0);
  p = fma(s2, p, 2.0/5.0); p = fma(s2, p, 2.0/3.0);
  double lm = fma(s * s2, p, 2.0 * s);
  return fma((double)e, 0.6931471805599453, lm);
}

// ---------------- full-ws fast path ----------------

// out f32 + h64 + hT (per-graph transpose) + sq row norms.
__global__ __launch_bounds__(256) void encoder_full(
    const float* __restrict__ x, const float* __restrict__ W,
    const float* __restrict__ b, float* __restrict__ out,
    double* __restrict__ h64, double* __restrict__ hT,
    double* __restrict__ sq){
  __shared__ float xs[512];
  const int tid = threadIdx.x;
  const size_t row0 = (size_t)blockIdx.x << 2;
  ((float2*)xs)[tid] = ((const float2*)(x + (row0 << 7)))[tid];
  __syncthreads();
  const int c = tid & 63, r = tid >> 6;
  double acc = (double)b[c];
  const float* xr = xs + (r << 7);
  #pragma unroll 16
  for (int k = 0; k < 128; ++k)
    acc += (double)xr[k] * (double)W[(k << 6) + c];
  const size_t row = row0 + (size_t)r;
  const size_t idx = (row << 6) + c;
  out[idx] = (float)acc;
  h64[idx] = acc;
  const size_t gb = row >> 10, lrow = row & 1023;
  hT[(((gb << 6) + (size_t)c) << 10) + lrow] = acc;
  double ss = acc * acc;                 // wave == one row (lane = c)
  #pragma unroll
  for (int off = 32; off; off >>= 1) ss += __shfl_xor(ss, off, 64);
  if (c == 0) sq[row] = ss;
}

// Block = 4 rows of graph gb. Dot-form distances (coalesced hT loads),
// fast exp/log, packed u64 keys (value-monotone, low 10 bits = 1023-j),
// per-wave top-16 via u64 max butterflies.
__global__ __launch_bounds__(256) void edges_fast(
    const double* __restrict__ h64, const double* __restrict__ hT,
    const double* __restrict__ sq, const float* __restrict__ temp,
    float* __restrict__ rows_out, float* __restrict__ cols_out){
  __shared__ __align__(16) double hi[4][64];
  __shared__ unsigned long long sv[4][1024];
  const int tid = threadIdx.x;
  const int gb = blockIdx.x >> 8;
  const int i0 = (blockIdx.x & 255) << 2;
  const double* __restrict__ hb = h64 + ((size_t)gb << 16);

  ((double*)hi)[tid] = hb[((size_t)i0 << 6) + tid];
  __syncthreads();

  const double T = (double)temp[0];
  const double* __restrict__ hTg = hT + ((size_t)gb << 16);
  const double* __restrict__ sqg = sq + ((size_t)gb << 10);

  double sqj[4], sqi[4];
  #pragma unroll
  for (int jj = 0; jj < 4; ++jj) sqj[jj] = sqg[(jj << 8) + tid];
  #pragma unroll
  for (int r = 0; r < 4; ++r) sqi[r] = sqg[i0 + r];

  double acc[4][4];
  #pragma unroll
  for (int r = 0; r < 4; ++r)
    #pragma unroll
    for (int jj = 0; jj < 4; ++jj) acc[r][jj] = 0.0;

  #pragma unroll 8
  for (int q = 0; q < 64; q += 2){
    double2 a[4];
    #pragma unroll
    for (int r = 0; r < 4; ++r) a[r] = *(const double2*)&hi[r][q];
    const double* col = hTg + ((size_t)q << 10) + tid;
    #pragma unroll
    for (int jj = 0; jj < 4; ++jj){
      double b0 = col[jj << 8];
      double b1 = col[(jj << 8) + 1024];
      #pragma unroll
      for (int r = 0; r < 4; ++r)
        acc[r][jj] = fma(a[r].x, b0, fma(a[r].y, b1, acc[r][jj]));
    }
  }

  const double T2 = T + T;
  #pragma unroll
  for (int r = 0; r < 4; ++r){
    const double tsi = T * sqi[r];
    #pragma unroll
    for (int jj = 0; jj < 4; ++jj){
      const int j = (jj << 8) + tid;
      double arg = fma(T2, acc[r][jj], -fma(T, sqj[jj], tsi));
      double sgm = fast_exp(arg);
      unsigned int e = ((unsigned int)gb << 20) |
                       ((unsigned int)(i0 + r) << 10) | (unsigned int)j;
      unsigned int bits = tf_bits_part(e);
      float f = __uint_as_float(0x3f800000u | (bits >> 9)) - 1.0f;
      double u = (f > 0.0f) ? (double)f : 1.1754943508222875e-38;
      double w = -fast_log(u);
      double z = -fast_log(w);
      double score = sgm + z;
      unsigned long long kb = (unsigned long long)__double_as_longlong(score);
      unsigned long long mask =
          (unsigned long long)(((long long)kb) >> 63) | 0x8000000000000000ull;
      kb ^= mask;
      kb = (kb & ~1023ull) | (unsigned long long)(1023 - j);
      sv[r][j] = kb;
    }
  }
  __syncthreads();

  const int wave = tid >> 6, lane = tid & 63;
  unsigned long long v[16];
  #pragma unroll
  for (int m = 0; m < 16; ++m) v[m] = sv[wave][(m << 6) + lane];

  const int grow = (gb << 10) + i0 + wave;
  float* rowp = rows_out + ((size_t)grow << 4);
  float* colp = cols_out + ((size_t)grow << 4);
  if (lane < 16) rowp[lane] = (float)grow;

  #pragma unroll 1
  for (int k = 0; k < 16; ++k){
    unsigned long long best = v[0];
    #pragma unroll
    for (int m = 1; m < 16; ++m) best = (v[m] > best) ? v[m] : best;
    #pragma unroll
    for (int off = 32; off; off >>= 1){
      unsigned long long o = __shfl_xor(best, off, 64);
      best = (o > best) ? o : best;
    }
    const int bj = 1023 - (int)(best & 1023ull);
    // invalidate winner without dynamic register indexing
    #pragma unroll
    for (int m = 0; m < 16; ++m) v[m] = (v[m] == best) ? 0ull : v[m];
    if (lane == 0) colp[k] = (float)((gb << 10) + bj);
  }
}

// ---------------- round-3 proven fallback ----------------

__device__ __forceinline__ double gumbel_z_ref(unsigned int bits){
  float f = __uint_as_float(0x3f800000u | (bits >> 9)) - 1.0f;
  double u = (f > 0.0f) ? (double)f : 1.1754943508222875e-38;
  return -log(-log(u));
}

__global__ __launch_bounds__(256) void encoder_kernel(
    const float* __restrict__ x, const float* __restrict__ W,
    const float* __restrict__ b, float* __restrict__ out,
    double* __restrict__ h64, int write64){
  __shared__ float xs[512];
  const int tid = threadIdx.x;
  const size_t row0 = (size_t)blockIdx.x << 2;
  ((float2*)xs)[tid] = ((const float2*)(x + (row0 << 7)))[tid];
  __syncthreads();
  const int c = tid & 63, r = tid >> 6;
  double acc = (double)b[c];
  const float* xr = xs + (r << 7);
  #pragma unroll 16
  for (int k = 0; k < 128; ++k)
    acc += (double)xr[k] * (double)W[(k << 6) + c];
  const size_t idx = ((row0 + (size_t)r) << 6) + c;
  out[idx] = (float)acc;
  if (write64) h64[idx] = acc;
}

template<typename T>
__global__ __launch_bounds__(256) void edges_kernel(
    const T* __restrict__ h, const float* __restrict__ temp,
    float* __restrict__ rows_out, float* __restrict__ cols_out){
  __shared__ double hi[4][64];
  __shared__ double sv[4][1024];
  const int tid = threadIdx.x;
  const int gb = blockIdx.x >> 8;
  const int i0 = (blockIdx.x & 255) << 2;
  const T* __restrict__ hbase = h + ((size_t)gb << 16);

  hi[tid >> 6][tid & 63] = (double)hbase[((size_t)i0 << 6) + tid];
  __syncthreads();

  const double Tmp = (double)temp[0];
  double acc[4][4];
  #pragma unroll
  for (int r = 0; r < 4; ++r)
    #pragma unroll
    for (int jj = 0; jj < 4; ++jj) acc[r][jj] = 0.0;

  #pragma unroll 1
  for (int jj = 0; jj < 4; ++jj){
    const T* __restrict__ hjr = hbase + (((size_t)(jj << 8) + tid) << 6);
    #pragma unroll 8
    for (int q = 0; q < 64; ++q){
      double bq = (double)hjr[q];
      #pragma unroll
      for (int r = 0; r < 4; ++r){
        double d = hi[r][q] - bq;
        acc[r][jj] = fma(d, d, acc[r][jj]);
      }
    }
  }

  #pragma unroll
  for (int r = 0; r < 4; ++r){
    #pragma unroll
    for (int jj = 0; jj < 4; ++jj){
      int j = (jj << 8) + tid;
      unsigned int e = ((unsigned int)gb << 20) |
                       ((unsigned int)(i0 + r) << 10) | (unsigned int)j;
      unsigned int bits = tf_bits_part(e);
      sv[r][j] = exp(-Tmp * acc[r][jj]) + gumbel_z_ref(bits);
    }
  }
  __syncthreads();

  const int wave = tid >> 6, lane = tid & 63;
  double v[16];
  #pragma unroll
  for (int m = 0; m < 16; ++m) v[m] = sv[wave][(m << 6) + lane];

  const int grow = (gb << 10) + i0 + wave;
  float* rowp = rows_out + ((size_t)grow << 4);
  float* colp = cols_out + ((size_t)grow << 4);
  if (lane < 16) rowp[lane] = (float)grow;

  #pragma unroll 1
  for (int k = 0; k < 16; ++k){
    double bv = -1.0e308; int bj = 1 << 30;
    #pragma unroll
    for (int m = 0; m < 16; ++m){
      int j = (m << 6) + lane;
      bool better = (v[m] > bv) || (v[m] == bv && j < bj);
      if (better){ bv = v[m]; bj = j; }
    }
    #pragma unroll
    for (int off = 32; off; off >>= 1){
      double ov = __shfl_xor(bv, off, 64);
      int    oj = __shfl_xor(bj, off, 64);
      bool better = (ov > bv) || (ov == bv && oj < bj);
      if (better){ bv = ov; bj = oj; }
    }
    if ((bj & 63) == lane) v[bj >> 6] = -1.0e308;
    if (lane == 0) colp[k] = (float)((gb << 10) + bj);
  }
}

extern "C" void kernel_launch(void* const* d_in, const int* in_sizes, int n_in,
                              void* d_out, int out_size, void* d_ws, size_t ws_size,
                              hipStream_t stream){
  const float* x = (const float*)d_in[0];
  const float* W = (const float*)d_in[1];
  const float* b = (const float*)d_in[2];
  const float* T = (const float*)d_in[3];
  float* out      = (float*)d_out;
  float* rows_out = out + OUT_ELEMS;
  float* cols_out = rows_out + EDGE_ELEMS;

  if (ws_size >= WS_FULL){
    double* h64 = (double*)d_ws;
    double* hT  = (double*)((char*)d_ws + H64_BYTES);
    double* sq  = (double*)((char*)d_ws + H64_BYTES + HT_BYTES);
    encoder_full<<<8192, 256, 0, stream>>>(x, W, b, out, h64, hT, sq);
    edges_fast<<<8192, 256, 0, stream>>>(h64, hT, sq, T, rows_out, cols_out);
  } else if (ws_size >= H64_BYTES){
    double* h64 = (double*)d_ws;
    encoder_kernel<<<8192, 256, 0, stream>>>(x, W, b, out, h64, 1);
    edges_kernel<double><<<8192, 256, 0, stream>>>(h64, T, rows_out, cols_out);
  } else {
    encoder_kernel<<<8192, 256, 0, stream>>>(x, W, b, out, (double*)d_ws, 0);
    edges_kernel<float><<<8192, 256, 0, stream>>>(out, T, rows_out, cols_out);
  }
}

// Round 5
// 611.285 us; speedup vs baseline: 1.2725x; 1.0679x over previous
//
#include <hip/hip_runtime.h>
#include <math.h>

// B=32 graphs, N=1024 nodes, D=128 in-dim, C=64 out-dim, K=16.
#define OUT_ELEMS 2097152   // 32768*64
#define EDGE_ELEMS 524288   // 32*1024*16
#define H64_BYTES (32768ull * 64ull * 8ull)   // 16 MiB f64 embeddings
#define HT_BYTES  (32768ull * 64ull * 8ull)   // 16 MiB transposed f64
#define SQ_BYTES  (32768ull * 8ull)           // 256 KiB row norms
#define WS_FULL   (H64_BYTES + HT_BYTES + SQ_BYTES)

__device__ __forceinline__ unsigned int rotl32(unsigned int x, int r){
  return (x << r) | (x >> (32 - r));
}

// JAX partitionable threefry, key (0,1): counter = (0, e); out = o0 ^ o1.
__device__ __forceinline__ unsigned int tf_bits_part(unsigned int e){
  unsigned int x0 = 0u, x1 = e;
  const unsigned int ks1 = 1u;
  const unsigned int ks2 = 0x1BD11BDBu;
  x1 += ks1;
#define TFR(r) { x0 += x1; x1 = rotl32(x1, r); x1 ^= x0; }
  TFR(13) TFR(15) TFR(26) TFR(6)
  x0 += ks1; x1 += ks2 + 1u;
  TFR(17) TFR(29) TFR(16) TFR(24)
  x0 += ks2; x1 += 0u + 2u;
  TFR(13) TFR(15) TFR(26) TFR(6)
  x0 += 0u;  x1 += ks1 + 3u;
  TFR(17) TFR(29) TFR(16) TFR(24)
  x0 += ks1; x1 += ks2 + 4u;
  TFR(13) TFR(15) TFR(26) TFR(6)
  x0 += ks2; x1 += 0u + 5u;
#undef TFR
  return x0 ^ x1;
}

// hardware f64 reciprocal + 2 Newton steps: rel err ~1e-16, ~6 f64 ops.
__device__ __forceinline__ double rcp64(double x){
  double r;
  asm("v_rcp_f64 %0, %1" : "=v"(r) : "v"(x));
  double e = fma(-x, r, 1.0); r = fma(r, e, r);
  e = fma(-x, r, 1.0); r = fma(r, e, r);
  return r;
}

// fast e^x for x in [-740, ~1]; rel err ~2e-11 (deg-9).
__device__ __forceinline__ double fast_exp(double x){
  double fn = __builtin_rint(x * 1.4426950408889634);
  int n = (int)fn;
  double r = fma(fn, -0.6931471803691238, x);
  r = fma(fn, -1.9082149292705877e-10, r);
  double p = 2.7557319223985893e-06;          // 1/9!
  p = fma(r, p, 2.4801587301587302e-05);      // 1/8!
  p = fma(r, p, 1.9841269841269841e-04);      // 1/7!
  p = fma(r, p, 1.3888888888888889e-03);      // 1/6!
  p = fma(r, p, 8.3333333333333333e-03);      // 1/5!
  p = fma(r, p, 4.1666666666666664e-02);      // 1/4!
  p = fma(r, p, 1.6666666666666666e-01);      // 1/3!
  p = fma(r, p, 0.5);
  p = fma(r, p, 1.0);
  p = fma(r, p, 1.0);
  double scale = __longlong_as_double(((long long)(n + 1023)) << 52);
  return p * scale;
}

// fast ln(x), normal positive x; atanh form, rcp-based; abs err ~2e-11.
__device__ __forceinline__ double fast_log(double x){
  long long bx = __double_as_longlong(x);
  long long e = (bx >> 52) - 1023;
  double m = __longlong_as_double((bx & 0xFFFFFFFFFFFFFll) |
                                  0x3FF0000000000000ll);
  int big = m > 1.4142135623730951;
  m = big ? 0.5 * m : m;
  e += big;
  double s = (m - 1.0) * rcp64(m + 1.0);
  double s2 = s * s;
  double p = fma(s2, 2.0/11.0, 2.0/9.0);
  p = fma(s2, p, 2.0/7.0);
  p = fma(s2, p, 2.0/5.0);
  p = fma(s2, p, 2.0/3.0);
  double lm = fma(s * s2, p, 2.0 * s);
  return fma((double)e, 0.6931471805599453, lm);
}

// ---------------- full-ws fast path ----------------

// out f32 + h64 + hT (per-graph transpose) + sq row norms.
__global__ __launch_bounds__(256) void encoder_full(
    const float* __restrict__ x, const float* __restrict__ W,
    const float* __restrict__ b, float* __restrict__ out,
    double* __restrict__ h64, double* __restrict__ hT,
    double* __restrict__ sq){
  __shared__ float xs[512];
  const int tid = threadIdx.x;
  const size_t row0 = (size_t)blockIdx.x << 2;
  ((float2*)xs)[tid] = ((const float2*)(x + (row0 << 7)))[tid];
  __syncthreads();
  const int c = tid & 63, r = tid >> 6;
  double acc = (double)b[c];
  const float* xr = xs + (r << 7);
  #pragma unroll 16
  for (int k = 0; k < 128; ++k)
    acc += (double)xr[k] * (double)W[(k << 6) + c];
  const size_t row = row0 + (size_t)r;
  const size_t idx = (row << 6) + c;
  out[idx] = (float)acc;
  h64[idx] = acc;
  const size_t gb = row >> 10, lrow = row & 1023;
  hT[(((gb << 6) + (size_t)c) << 10) + lrow] = acc;
  double ss = acc * acc;                 // wave == one row (lane = c)
  #pragma unroll
  for (int off = 32; off; off >>= 1) ss += __shfl_xor(ss, off, 64);
  if (c == 0) sq[row] = ss;
}

// Block = 4 rows of graph gb. Dot-form distances with 4-row load reuse;
// epilogue + top-k split into 2 halves so sv is only 2 rows (LDS 18.4 KB
// -> 6+ blocks/CU). Per-wave top-16 via packed u64 keys, incremental
// per-lane max (winner lane alone rescans, exec-masked).
__global__ __launch_bounds__(256, 6) void edges_fast(
    const double* __restrict__ h64, const double* __restrict__ hT,
    const double* __restrict__ sq, const float* __restrict__ temp,
    float* __restrict__ rows_out, float* __restrict__ cols_out){
  __shared__ __align__(16) double hi[4][64];                 // 2 KB
  __shared__ unsigned long long sv[2][1024];                 // 16 KB
  const int tid = threadIdx.x;
  const int wave = tid >> 6, lane = tid & 63;
  const int gb = blockIdx.x >> 8;
  const int i0 = (blockIdx.x & 255) << 2;
  const double* __restrict__ hb = h64 + ((size_t)gb << 16);

  ((double*)hi)[tid] = hb[((size_t)i0 << 6) + tid];
  __syncthreads();

  const double T = (double)temp[0];
  const double* __restrict__ hTg = hT + ((size_t)gb << 16);
  const double* __restrict__ sqg = sq + ((size_t)gb << 10);

  double sqj[4], sqi[4];
  #pragma unroll
  for (int jj = 0; jj < 4; ++jj) sqj[jj] = sqg[(jj << 8) + tid];
  #pragma unroll
  for (int r = 0; r < 4; ++r) sqi[r] = sqg[i0 + r];

  double acc[4][4];
  #pragma unroll
  for (int r = 0; r < 4; ++r)
    #pragma unroll
    for (int jj = 0; jj < 4; ++jj) acc[r][jj] = 0.0;

  #pragma unroll 8
  for (int q = 0; q < 64; q += 2){
    double2 a[4];
    #pragma unroll
    for (int r = 0; r < 4; ++r) a[r] = *(const double2*)&hi[r][q];
    const double* col = hTg + ((size_t)q << 10) + tid;
    #pragma unroll
    for (int jj = 0; jj < 4; ++jj){
      double b0 = col[jj << 8];
      double b1 = col[(jj << 8) + 1024];
      #pragma unroll
      for (int r = 0; r < 4; ++r)
        acc[r][jj] = fma(a[r].x, b0, fma(a[r].y, b1, acc[r][jj]));
    }
  }

  const double T2 = T + T;
  #pragma unroll
  for (int half = 0; half < 2; ++half){
    // scores for rows 2*half, 2*half+1 into sv[0..1]
    #pragma unroll
    for (int rr = 0; rr < 2; ++rr){
      const int r = (half << 1) + rr;
      const double tsi = T * sqi[r];
      #pragma unroll
      for (int jj = 0; jj < 4; ++jj){
        const int j = (jj << 8) + tid;
        double arg = fma(T2, acc[r][jj], -fma(T, sqj[jj], tsi));
        double sgm = fast_exp(arg);
        unsigned int e = ((unsigned int)gb << 20) |
                         ((unsigned int)(i0 + r) << 10) | (unsigned int)j;
        unsigned int bits = tf_bits_part(e);
        float f = __uint_as_float(0x3f800000u | (bits >> 9)) - 1.0f;
        double u = (f > 0.0f) ? (double)f : 1.1754943508222875e-38;
        double w = -fast_log(u);
        double z = -fast_log(w);
        double score = sgm + z;
        unsigned long long kb = (unsigned long long)__double_as_longlong(score);
        unsigned long long mask =
            (unsigned long long)(((long long)kb) >> 63) | 0x8000000000000000ull;
        kb ^= mask;
        kb = (kb & ~1023ull) | (unsigned long long)(1023 - j);
        sv[rr][j] = kb;
      }
    }
    __syncthreads();

    // waves 0-1 select in half 0 (rows i0+0,1); waves 2-3 in half 1.
    if ((wave >> 1) == half){
      const int rloc = (half << 1) + (wave & 1);
      unsigned long long v[16];
      #pragma unroll
      for (int m = 0; m < 16; ++m) v[m] = sv[wave & 1][(m << 6) + lane];
      unsigned long long lm = v[0];
      #pragma unroll
      for (int m = 1; m < 16; ++m) lm = (v[m] > lm) ? v[m] : lm;

      const int grow = (gb << 10) + i0 + rloc;
      float* rowp = rows_out + ((size_t)grow << 4);
      float* colp = cols_out + ((size_t)grow << 4);
      if (lane < 16) rowp[lane] = (float)grow;

      #pragma unroll 1
      for (int k = 0; k < 16; ++k){
        unsigned long long best = lm;
        #pragma unroll
        for (int off = 32; off; off >>= 1){
          unsigned long long o = __shfl_xor(best, off, 64);
          best = (o > best) ? o : best;
        }
        const int bj = 1023 - (int)(best & 1023ull);
        if (lane == 0) colp[k] = (float)((gb << 10) + bj);
        if ((bj & 63) == lane){
          // winner lane: invalidate + rescan (keys unique; merged pass)
          unsigned long long nm = 0ull;
          #pragma unroll
          for (int m = 0; m < 16; ++m){
            v[m] = (v[m] == best) ? 0ull : v[m];
            nm = (v[m] > nm) ? v[m] : nm;
          }
          lm = nm;
        }
      }
    }
    __syncthreads();
  }
}

// ---------------- proven fallbacks (small ws) ----------------

__device__ __forceinline__ double gumbel_z_ref(unsigned int bits){
  float f = __uint_as_float(0x3f800000u | (bits >> 9)) - 1.0f;
  double u = (f > 0.0f) ? (double)f : 1.1754943508222875e-38;
  return -log(-log(u));
}

__global__ __launch_bounds__(256) void encoder_kernel(
    const float* __restrict__ x, const float* __restrict__ W,
    const float* __restrict__ b, float* __restrict__ out,
    double* __restrict__ h64, int write64){
  __shared__ float xs[512];
  const int tid = threadIdx.x;
  const size_t row0 = (size_t)blockIdx.x << 2;
  ((float2*)xs)[tid] = ((const float2*)(x + (row0 << 7)))[tid];
  __syncthreads();
  const int c = tid & 63, r = tid >> 6;
  double acc = (double)b[c];
  const float* xr = xs + (r << 7);
  #pragma unroll 16
  for (int k = 0; k < 128; ++k)
    acc += (double)xr[k] * (double)W[(k << 6) + c];
  const size_t idx = ((row0 + (size_t)r) << 6) + c;
  out[idx] = (float)acc;
  if (write64) h64[idx] = acc;
}

template<typename T>
__global__ __launch_bounds__(256) void edges_kernel(
    const T* __restrict__ h, const float* __restrict__ temp,
    float* __restrict__ rows_out, float* __restrict__ cols_out){
  __shared__ double hi[4][64];
  __shared__ double sv[4][1024];
  const int tid = threadIdx.x;
  const int gb = blockIdx.x >> 8;
  const int i0 = (blockIdx.x & 255) << 2;
  const T* __restrict__ hbase = h + ((size_t)gb << 16);

  hi[tid >> 6][tid & 63] = (double)hbase[((size_t)i0 << 6) + tid];
  __syncthreads();

  const double Tmp = (double)temp[0];
  double acc[4][4];
  #pragma unroll
  for (int r = 0; r < 4; ++r)
    #pragma unroll
    for (int jj = 0; jj < 4; ++jj) acc[r][jj] = 0.0;

  #pragma unroll 1
  for (int jj = 0; jj < 4; ++jj){
    const T* __restrict__ hjr = hbase + (((size_t)(jj << 8) + tid) << 6);
    #pragma unroll 8
    for (int q = 0; q < 64; ++q){
      double bq = (double)hjr[q];
      #pragma unroll
      for (int r = 0; r < 4; ++r){
        double d = hi[r][q] - bq;
        acc[r][jj] = fma(d, d, acc[r][jj]);
      }
    }
  }

  #pragma unroll
  for (int r = 0; r < 4; ++r){
    #pragma unroll
    for (int jj = 0; jj < 4; ++jj){
      int j = (jj << 8) + tid;
      unsigned int e = ((unsigned int)gb << 20) |
                       ((unsigned int)(i0 + r) << 10) | (unsigned int)j;
      unsigned int bits = tf_bits_part(e);
      sv[r][j] = exp(-Tmp * acc[r][jj]) + gumbel_z_ref(bits);
    }
  }
  __syncthreads();

  const int wave = tid >> 6, lane = tid & 63;
  double v[16];
  #pragma unroll
  for (int m = 0; m < 16; ++m) v[m] = sv[wave][(m << 6) + lane];

  const int grow = (gb << 10) + i0 + wave;
  float* rowp = rows_out + ((size_t)grow << 4);
  float* colp = cols_out + ((size_t)grow << 4);
  if (lane < 16) rowp[lane] = (float)grow;

  #pragma unroll 1
  for (int k = 0; k < 16; ++k){
    double bv = -1.0e308; int bj = 1 << 30;
    #pragma unroll
    for (int m = 0; m < 16; ++m){
      int j = (m << 6) + lane;
      bool better = (v[m] > bv) || (v[m] == bv && j < bj);
      if (better){ bv = v[m]; bj = j; }
    }
    #pragma unroll
    for (int off = 32; off; off >>= 1){
      double ov = __shfl_xor(bv, off, 64);
      int    oj = __shfl_xor(bj, off, 64);
      bool better = (ov > bv) || (ov == bv && oj < bj);
      if (better){ bv = ov; bj = oj; }
    }
    if ((bj & 63) == lane) v[bj >> 6] = -1.0e308;
    if (lane == 0) colp[k] = (float)((gb << 10) + bj);
  }
}

extern "C" void kernel_launch(void* const* d_in, const int* in_sizes, int n_in,
                              void* d_out, int out_size, void* d_ws, size_t ws_size,
                              hipStream_t stream){
  const float* x = (const float*)d_in[0];
  const float* W = (const float*)d_in[1];
  const float* b = (const float*)d_in[2];
  const float* T = (const float*)d_in[3];
  float* out      = (float*)d_out;
  float* rows_out = out + OUT_ELEMS;
  float* cols_out = rows_out + EDGE_ELEMS;

  if (ws_size >= WS_FULL){
    double* h64 = (double*)d_ws;
    double* hT  = (double*)((char*)d_ws + H64_BYTES);
    double* sq  = (double*)((char*)d_ws + H64_BYTES + HT_BYTES);
    encoder_full<<<8192, 256, 0, stream>>>(x, W, b, out, h64, hT, sq);
    edges_fast<<<8192, 256, 0, stream>>>(h64, hT, sq, T, rows_out, cols_out);
  } else if (ws_size >= H64_BYTES){
    double* h64 = (double*)d_ws;
    encoder_kernel<<<8192, 256, 0, stream>>>(x, W, b, out, h64, 1);
    edges_kernel<double><<<8192, 256, 0, stream>>>(h64, T, rows_out, cols_out);
  } else {
    encoder_kernel<<<8192, 256, 0, stream>>>(x, W, b, out, (double*)d_ws, 0);
    edges_kernel<float><<<8192, 256, 0, stream>>>(out, T, rows_out, cols_out);
  }
}

// Round 6
// 461.609 us; speedup vs baseline: 1.6851x; 1.3242x over previous
//
#include <hip/hip_runtime.h>
#include <math.h>

// B=32 graphs, N=1024 nodes, D=128 in-dim, C=64 out-dim, K=16.
#define OUT_ELEMS 2097152   // 32768*64
#define EDGE_ELEMS 524288   // 32*1024*16
#define HT32_BYTES (32768ull * 64ull * 4ull)   // 8 MiB f32 transposed h
#define SQ32_BYTES (32768ull * 4ull)           // 128 KiB f32 row norms
#define WS_NEED (HT32_BYTES + SQ32_BYTES)

__device__ __forceinline__ unsigned int rotl32(unsigned int x, int r){
  return (x << r) | (x >> (32 - r));
}

// JAX partitionable threefry, key (0,1): counter = (0, e); out = o0 ^ o1.
__device__ __forceinline__ unsigned int tf_bits_part(unsigned int e){
  unsigned int x0 = 0u, x1 = e;
  const unsigned int ks1 = 1u;
  const unsigned int ks2 = 0x1BD11BDBu;
  x1 += ks1;
#define TFR(r) { x0 += x1; x1 = rotl32(x1, r); x1 ^= x0; }
  TFR(13) TFR(15) TFR(26) TFR(6)
  x0 += ks1; x1 += ks2 + 1u;
  TFR(17) TFR(29) TFR(16) TFR(24)
  x0 += ks2; x1 += 0u + 2u;
  TFR(13) TFR(15) TFR(26) TFR(6)
  x0 += 0u;  x1 += ks1 + 3u;
  TFR(17) TFR(29) TFR(16) TFR(24)
  x0 += ks1; x1 += ks2 + 4u;
  TFR(13) TFR(15) TFR(26) TFR(6)
  x0 += ks2; x1 += 0u + 5u;
#undef TFR
  return x0 ^ x1;
}

// hardware f64 reciprocal + 2 Newton steps: rel err ~1e-16.
__device__ __forceinline__ double rcp64(double x){
  double r;
  asm("v_rcp_f64 %0, %1" : "=v"(r) : "v"(x));
  double e = fma(-x, r, 1.0); r = fma(r, e, r);
  e = fma(-x, r, 1.0); r = fma(r, e, r);
  return r;
}

// fast e^x for x in [-740, ~1]; rel err ~2e-11 (deg-9).
__device__ __forceinline__ double fast_exp(double x){
  double fn = __builtin_rint(x * 1.4426950408889634);
  int n = (int)fn;
  double r = fma(fn, -0.6931471803691238, x);
  r = fma(fn, -1.9082149292705877e-10, r);
  double p = 2.7557319223985893e-06;
  p = fma(r, p, 2.4801587301587302e-05);
  p = fma(r, p, 1.9841269841269841e-04);
  p = fma(r, p, 1.3888888888888889e-03);
  p = fma(r, p, 8.3333333333333333e-03);
  p = fma(r, p, 4.1666666666666664e-02);
  p = fma(r, p, 1.6666666666666666e-01);
  p = fma(r, p, 0.5);
  p = fma(r, p, 1.0);
  p = fma(r, p, 1.0);
  double scale = __longlong_as_double(((long long)(n + 1023)) << 52);
  return p * scale;
}

// fast ln(x), normal positive x; atanh form; abs err ~2e-11.
__device__ __forceinline__ double fast_log(double x){
  long long bx = __double_as_longlong(x);
  long long e = (bx >> 52) - 1023;
  double m = __longlong_as_double((bx & 0xFFFFFFFFFFFFFll) |
                                  0x3FF0000000000000ll);
  int big = m > 1.4142135623730951;
  m = big ? 0.5 * m : m;
  e += big;
  double s = (m - 1.0) * rcp64(m + 1.0);
  double s2 = s * s;
  double p = fma(s2, 2.0/11.0, 2.0/9.0);
  p = fma(s2, p, 2.0/7.0);
  p = fma(s2, p, 2.0/5.0);
  p = fma(s2, p, 2.0/3.0);
  double lm = fma(s * s2, p, 2.0 * s);
  return fma((double)e, 0.6931471805599453, lm);
}

// ---------------- fast path ----------------

// out = f32(x@W+b); hT32 = per-graph transposed f32 out; sq32 = row norms.
__global__ __launch_bounds__(256) void encoder_v3(
    const float* __restrict__ x, const float* __restrict__ W,
    const float* __restrict__ b, float* __restrict__ out,
    float* __restrict__ hT32, float* __restrict__ sq32){
  __shared__ float xs[512];
  const int tid = threadIdx.x;
  const size_t row0 = (size_t)blockIdx.x << 2;
  ((float2*)xs)[tid] = ((const float2*)(x + (row0 << 7)))[tid];
  __syncthreads();
  const int c = tid & 63, r = tid >> 6;
  double acc = (double)b[c];
  const float* xr = xs + (r << 7);
  #pragma unroll 16
  for (int k = 0; k < 128; ++k)
    acc += (double)xr[k] * (double)W[(k << 6) + c];
  const size_t row = row0 + (size_t)r;
  const float o = (float)acc;
  out[(row << 6) + c] = o;
  const size_t gb = row >> 10, lrow = row & 1023;
  hT32[(((gb << 6) + (size_t)c) << 10) + lrow] = o;
  float ss = o * o;                      // wave == one row (lane = c)
  #pragma unroll
  for (int off = 32; off; off >>= 1) ss += __shfl_xor(ss, off, 64);
  if (c == 0) sq32[row] = ss;
}

// Block = 8 rows of graph gb. Phase A: f32 scores -> u32 keys (index in low
// 10 bits). Phase B (per wave, per row): top-24 u32 selection, then exact
// f64 re-score of the 24 candidates from f32-rounded h, final top-16 on
// exact u64 keys. Candidate buffer of 24 provably covers the exact top-16
// (key quantization 2e-3 vs rank-16->25 gap ~0.45).
__global__ __launch_bounds__(256, 4) void edges_v3(
    const float* __restrict__ out32, const float* __restrict__ hT32,
    const float* __restrict__ sq32, const float* __restrict__ temp,
    float* __restrict__ rows_out, float* __restrict__ cols_out){
  __shared__ __align__(16) float hi[8][64];     // 2 KB
  __shared__ unsigned int sv[4][1024];          // 16 KB
  const int tid = threadIdx.x, wave = tid >> 6, lane = tid & 63;
  const int gb = blockIdx.x >> 7;
  const int i0 = (blockIdx.x & 127) << 3;

  const float* src = out32 + ((((size_t)gb << 10) + i0) << 6);
  ((float2*)hi)[tid] = ((const float2*)src)[tid];
  __syncthreads();

  const float  Tf = temp[0];
  const double Td = (double)temp[0];
  const float* hTg = hT32 + ((size_t)gb << 16);
  const float* sqg = sq32 + ((size_t)gb << 10);

  float sqjv[4], sqiv[8];
  #pragma unroll
  for (int jj = 0; jj < 4; ++jj) sqjv[jj] = sqg[(jj << 8) + tid];
  #pragma unroll
  for (int r = 0; r < 8; ++r) sqiv[r] = sqg[i0 + r];

  float acc[8][4];
  #pragma unroll
  for (int r = 0; r < 8; ++r)
    #pragma unroll
    for (int jj = 0; jj < 4; ++jj) acc[r][jj] = 0.0f;

  #pragma unroll 1
  for (int q = 0; q < 64; q += 4){
    float4 a[8];
    #pragma unroll
    for (int r = 0; r < 8; ++r) a[r] = *(const float4*)&hi[r][q];
    const float* col = hTg + ((size_t)q << 10) + tid;
    #pragma unroll
    for (int jj = 0; jj < 4; ++jj){
      float b0 = col[(jj << 8)];
      float b1 = col[(jj << 8) + 1024];
      float b2 = col[(jj << 8) + 2048];
      float b3 = col[(jj << 8) + 3072];
      #pragma unroll
      for (int r = 0; r < 8; ++r)
        acc[r][jj] = fmaf(a[r].x, b0, fmaf(a[r].y, b1,
                     fmaf(a[r].z, b2, fmaf(a[r].w, b3, acc[r][jj]))));
    }
  }

  const float T2f = Tf + Tf;
  #pragma unroll 1
  for (int half = 0; half < 2; ++half){
    #pragma unroll
    for (int rr = 0; rr < 4; ++rr){
      const int r = (half << 2) + rr;
      const float tsi = Tf * sqiv[r];
      #pragma unroll
      for (int jj = 0; jj < 4; ++jj){
        const int j = (jj << 8) + tid;
        float arg = fmaf(T2f, acc[r][jj], -fmaf(Tf, sqjv[jj], tsi));
        float sgm = __expf(arg);
        unsigned int e = ((unsigned int)gb << 20) |
                         ((unsigned int)(i0 + r) << 10) | (unsigned int)j;
        unsigned int bits = tf_bits_part(e);
        float uf = __uint_as_float(0x3f800000u | (bits >> 9)) - 1.0f;
        uf = (uf > 0.0f) ? uf : 1.17549435e-38f;
        float z = -__logf(-__logf(uf));
        float s = sgm + z;
        unsigned int kb = __float_as_uint(s);
        kb ^= (unsigned int)(((int)kb) >> 31) | 0x80000000u;
        kb = (kb & ~1023u) | (unsigned int)(1023 - j);
        sv[rr][j] = kb;
      }
    }
    __syncthreads();

    { // wave handles row half*4 + wave
      const int r = (half << 2) + wave;
      const int grow = (gb << 10) + i0 + r;
      unsigned int v[16];
      #pragma unroll
      for (int m = 0; m < 16; ++m) v[m] = sv[wave][(m << 6) + lane];
      unsigned int lm = v[0];
      #pragma unroll
      for (int m = 1; m < 16; ++m) lm = (v[m] > lm) ? v[m] : lm;

      int myj = 0;
      #pragma unroll 1
      for (int c = 0; c < 24; ++c){
        unsigned int best = lm;
        #pragma unroll
        for (int off = 32; off; off >>= 1){
          unsigned int o = __shfl_xor(best, off, 64);
          best = (o > best) ? o : best;
        }
        const int bj = 1023 - (int)(best & 1023u);
        if (c == lane) myj = bj;
        if ((bj & 63) == lane){
          unsigned int nm = 0u;
          #pragma unroll
          for (int m = 0; m < 16; ++m){
            v[m] = (v[m] == best) ? 0u : v[m];
            nm = (v[m] > nm) ? v[m] : nm;
          }
          lm = nm;
        }
      }

      // exact f64 re-score of 24 candidates from f32-rounded h
      const float* og = out32 + ((size_t)gb << 16);
      const double hiv = (double)og[((size_t)(i0 + r) << 6) + lane];
      double darg = 0.0;
      #pragma unroll 1
      for (int c = 0; c < 24; ++c){
        int jc = __shfl(myj, c, 64);
        double d = hiv - (double)og[((size_t)jc << 6) + lane];
        double p = d * d;
        #pragma unroll
        for (int off = 32; off; off >>= 1) p += __shfl_xor(p, off, 64);
        if (lane == c) darg = p;
      }
      unsigned long long key = 0ull;
      if (lane < 24){
        double sgm = fast_exp(-Td * darg);
        unsigned int e = ((unsigned int)gb << 20) |
                         ((unsigned int)(i0 + r) << 10) | (unsigned int)myj;
        unsigned int bits = tf_bits_part(e);
        float f = __uint_as_float(0x3f800000u | (bits >> 9)) - 1.0f;
        double u = (f > 0.0f) ? (double)f : 1.1754943508222875e-38;
        double w = -fast_log(u);
        double z = -fast_log(w);
        double s = sgm + z;
        unsigned long long kb = (unsigned long long)__double_as_longlong(s);
        kb ^= (unsigned long long)(((long long)kb) >> 63) |
              0x8000000000000000ull;
        key = (kb & ~1023ull) | (unsigned long long)(1023 - myj);
      }
      float* rowp = rows_out + ((size_t)grow << 4);
      float* colp = cols_out + ((size_t)grow << 4);
      if (lane < 16) rowp[lane] = (float)grow;
      #pragma unroll 1
      for (int k = 0; k < 16; ++k){
        unsigned long long best = key;
        #pragma unroll
        for (int off = 32; off; off >>= 1){
          unsigned long long o = __shfl_xor(best, off, 64);
          best = (o > best) ? o : best;
        }
        if (lane == 0)
          colp[k] = (float)((gb << 10) + (1023 - (int)(best & 1023ull)));
        key = (key == best) ? 0ull : key;
      }
    }
    __syncthreads();
  }
}

// ---------------- proven fallback (tiny ws): full f64 from f32 h ----------------

__device__ __forceinline__ double gumbel_z_ref(unsigned int bits){
  float f = __uint_as_float(0x3f800000u | (bits >> 9)) - 1.0f;
  double u = (f > 0.0f) ? (double)f : 1.1754943508222875e-38;
  return -log(-log(u));
}

__global__ __launch_bounds__(256) void encoder_kernel(
    const float* __restrict__ x, const float* __restrict__ W,
    const float* __restrict__ b, float* __restrict__ out){
  __shared__ float xs[512];
  const int tid = threadIdx.x;
  const size_t row0 = (size_t)blockIdx.x << 2;
  ((float2*)xs)[tid] = ((const float2*)(x + (row0 << 7)))[tid];
  __syncthreads();
  const int c = tid & 63, r = tid >> 6;
  double acc = (double)b[c];
  const float* xr = xs + (r << 7);
  #pragma unroll 16
  for (int k = 0; k < 128; ++k)
    acc += (double)xr[k] * (double)W[(k << 6) + c];
  out[((row0 + (size_t)r) << 6) + c] = (float)acc;
}

__global__ __launch_bounds__(256) void edges_kernel(
    const float* __restrict__ h, const float* __restrict__ temp,
    float* __restrict__ rows_out, float* __restrict__ cols_out){
  __shared__ double hi[4][64];
  __shared__ double sv[4][1024];
  const int tid = threadIdx.x;
  const int gb = blockIdx.x >> 8;
  const int i0 = (blockIdx.x & 255) << 2;
  const float* __restrict__ hbase = h + ((size_t)gb << 16);

  hi[tid >> 6][tid & 63] = (double)hbase[((size_t)i0 << 6) + tid];
  __syncthreads();

  const double Tmp = (double)temp[0];
  double acc[4][4];
  #pragma unroll
  for (int r = 0; r < 4; ++r)
    #pragma unroll
    for (int jj = 0; jj < 4; ++jj) acc[r][jj] = 0.0;

  #pragma unroll 1
  for (int jj = 0; jj < 4; ++jj){
    const float* __restrict__ hjr = hbase + (((size_t)(jj << 8) + tid) << 6);
    #pragma unroll 8
    for (int q = 0; q < 64; ++q){
      double bq = (double)hjr[q];
      #pragma unroll
      for (int r = 0; r < 4; ++r){
        double d = hi[r][q] - bq;
        acc[r][jj] = fma(d, d, acc[r][jj]);
      }
    }
  }

  #pragma unroll
  for (int r = 0; r < 4; ++r){
    #pragma unroll
    for (int jj = 0; jj < 4; ++jj){
      int j = (jj << 8) + tid;
      unsigned int e = ((unsigned int)gb << 20) |
                       ((unsigned int)(i0 + r) << 10) | (unsigned int)j;
      unsigned int bits = tf_bits_part(e);
      sv[r][j] = exp(-Tmp * acc[r][jj]) + gumbel_z_ref(bits);
    }
  }
  __syncthreads();

  const int wave = tid >> 6, lane = tid & 63;
  double v[16];
  #pragma unroll
  for (int m = 0; m < 16; ++m) v[m] = sv[wave][(m << 6) + lane];

  const int grow = (gb << 10) + i0 + wave;
  float* rowp = rows_out + ((size_t)grow << 4);
  float* colp = cols_out + ((size_t)grow << 4);
  if (lane < 16) rowp[lane] = (float)grow;

  #pragma unroll 1
  for (int k = 0; k < 16; ++k){
    double bv = -1.0e308; int bj = 1 << 30;
    #pragma unroll
    for (int m = 0; m < 16; ++m){
      int j = (m << 6) + lane;
      bool better = (v[m] > bv) || (v[m] == bv && j < bj);
      if (better){ bv = v[m]; bj = j; }
    }
    #pragma unroll
    for (int off = 32; off; off >>= 1){
      double ov = __shfl_xor(bv, off, 64);
      int    oj = __shfl_xor(bj, off, 64);
      bool better = (ov > bv) || (ov == bv && oj < bj);
      if (better){ bv = ov; bj = oj; }
    }
    if ((bj & 63) == lane) v[bj >> 6] = -1.0e308;
    if (lane == 0) colp[k] = (float)((gb << 10) + bj);
  }
}

extern "C" void kernel_launch(void* const* d_in, const int* in_sizes, int n_in,
                              void* d_out, int out_size, void* d_ws, size_t ws_size,
                              hipStream_t stream){
  const float* x = (const float*)d_in[0];
  const float* W = (const float*)d_in[1];
  const float* b = (const float*)d_in[2];
  const float* T = (const float*)d_in[3];
  float* out      = (float*)d_out;
  float* rows_out = out + OUT_ELEMS;
  float* cols_out = rows_out + EDGE_ELEMS;

  if (ws_size >= WS_NEED){
    float* hT32 = (float*)d_ws;
    float* sq32 = (float*)((char*)d_ws + HT32_BYTES);
    encoder_v3<<<8192, 256, 0, stream>>>(x, W, b, out, hT32, sq32);
    edges_v3<<<4096, 256, 0, stream>>>(out, hT32, sq32, T, rows_out, cols_out);
  } else {
    encoder_kernel<<<8192, 256, 0, stream>>>(x, W, b, out);
    edges_kernel<<<8192, 256, 0, stream>>>(out, T, rows_out, cols_out);
  }
}

// Round 7
// 373.236 us; speedup vs baseline: 2.0841x; 1.2368x over previous
//
#include <hip/hip_runtime.h>
#include <math.h>

// B=32 graphs, N=1024 nodes, D=128 in-dim, C=64 out-dim, K=16.
#define OUT_ELEMS 2097152   // 32768*64
#define EDGE_ELEMS 524288   // 32*1024*16
#define HT32_BYTES (32768ull * 64ull * 4ull)   // 8 MiB f32 transposed h
#define SQ32_BYTES (32768ull * 4ull)           // 128 KiB f32 row norms
#define WS_NEED (HT32_BYTES + SQ32_BYTES)

__device__ __forceinline__ unsigned int rotl32(unsigned int x, int r){
  return (x << r) | (x >> (32 - r));
}

// JAX partitionable threefry, key (0,1): counter = (0, e); out = o0 ^ o1.
__device__ __forceinline__ unsigned int tf_bits_part(unsigned int e){
  unsigned int x0 = 0u, x1 = e;
  const unsigned int ks1 = 1u;
  const unsigned int ks2 = 0x1BD11BDBu;
  x1 += ks1;
#define TFR(r) { x0 += x1; x1 = rotl32(x1, r); x1 ^= x0; }
  TFR(13) TFR(15) TFR(26) TFR(6)
  x0 += ks1; x1 += ks2 + 1u;
  TFR(17) TFR(29) TFR(16) TFR(24)
  x0 += ks2; x1 += 0u + 2u;
  TFR(13) TFR(15) TFR(26) TFR(6)
  x0 += 0u;  x1 += ks1 + 3u;
  TFR(17) TFR(29) TFR(16) TFR(24)
  x0 += ks1; x1 += ks2 + 4u;
  TFR(13) TFR(15) TFR(26) TFR(6)
  x0 += ks2; x1 += 0u + 5u;
#undef TFR
  return x0 ^ x1;
}

// hardware f64 reciprocal + 2 Newton steps: rel err ~1e-16.
__device__ __forceinline__ double rcp64(double x){
  double r;
  asm("v_rcp_f64 %0, %1" : "=v"(r) : "v"(x));
  double e = fma(-x, r, 1.0); r = fma(r, e, r);
  e = fma(-x, r, 1.0); r = fma(r, e, r);
  return r;
}

// fast e^x for x in [-740, ~1]; rel err ~2e-11 (deg-9).
__device__ __forceinline__ double fast_exp(double x){
  double fn = __builtin_rint(x * 1.4426950408889634);
  int n = (int)fn;
  double r = fma(fn, -0.6931471803691238, x);
  r = fma(fn, -1.9082149292705877e-10, r);
  double p = 2.7557319223985893e-06;
  p = fma(r, p, 2.4801587301587302e-05);
  p = fma(r, p, 1.9841269841269841e-04);
  p = fma(r, p, 1.3888888888888889e-03);
  p = fma(r, p, 8.3333333333333333e-03);
  p = fma(r, p, 4.1666666666666664e-02);
  p = fma(r, p, 1.6666666666666666e-01);
  p = fma(r, p, 0.5);
  p = fma(r, p, 1.0);
  p = fma(r, p, 1.0);
  double scale = __longlong_as_double(((long long)(n + 1023)) << 52);
  return p * scale;
}

// fast ln(x), normal positive x; atanh form; abs err ~2e-11.
__device__ __forceinline__ double fast_log(double x){
  long long bx = __double_as_longlong(x);
  long long e = (bx >> 52) - 1023;
  double m = __longlong_as_double((bx & 0xFFFFFFFFFFFFFll) |
                                  0x3FF0000000000000ll);
  int big = m > 1.4142135623730951;
  m = big ? 0.5 * m : m;
  e += big;
  double s = (m - 1.0) * rcp64(m + 1.0);
  double s2 = s * s;
  double p = fma(s2, 2.0/11.0, 2.0/9.0);
  p = fma(s2, p, 2.0/7.0);
  p = fma(s2, p, 2.0/5.0);
  p = fma(s2, p, 2.0/3.0);
  double lm = fma(s * s2, p, 2.0 * s);
  return fma((double)e, 0.6931471805599453, lm);
}

// ---------------- fast path ----------------

// Block = 64 rows of one graph. f64-accumulated GEMM from LDS tiles
// (sequential-k order => bit-identical out), coalesced out writes,
// LDS-staged transpose (pad 65) for coalesced hT32 writes, sq butterfly
// in the original lane order.
__global__ __launch_bounds__(256) void encoder_v4(
    const float* __restrict__ x, const float* __restrict__ W,
    const float* __restrict__ b, float* __restrict__ out,
    float* __restrict__ hT32, float* __restrict__ sq32){
  __shared__ float xs[8192];   // 64 rows x 128 (reused as ldsT[64][65])
  __shared__ float ws[8192];   // 128 x 64
  const int tid = threadIdx.x;
  const int w = tid >> 6, c = tid & 63;
  const size_t r0 = (size_t)blockIdx.x << 6;     // 64 rows per block
  const int gb = (int)(r0 >> 10);
  const int lr0 = (int)(r0 & 1023);

  { // stage x tile + W (coalesced float4)
    const float4* xg4 = (const float4*)(x + (r0 << 7));
    const float4* wg4 = (const float4*)W;
    float4* xs4 = (float4*)xs;
    float4* ws4 = (float4*)ws;
    #pragma unroll
    for (int s = 0; s < 8; ++s){
      xs4[tid + (s << 8)] = xg4[tid + (s << 8)];
      ws4[tid + (s << 8)] = wg4[tid + (s << 8)];
    }
  }
  __syncthreads();

  // wave w computes rows w*16..w*16+15, column c (f64, k-sequential)
  double acc[16];
  const double bc = (double)b[c];
  #pragma unroll
  for (int i = 0; i < 16; ++i) acc[i] = bc;

  #pragma unroll 4
  for (int k = 0; k < 128; k += 4){
    const double w0 = (double)ws[((k + 0) << 6) + c];
    const double w1 = (double)ws[((k + 1) << 6) + c];
    const double w2 = (double)ws[((k + 2) << 6) + c];
    const double w3 = (double)ws[((k + 3) << 6) + c];
    #pragma unroll
    for (int i = 0; i < 16; ++i){
      const float4 xv = *(const float4*)&xs[(((w << 4) + i) << 7) + k];
      acc[i] = fma((double)xv.x, w0, acc[i]);
      acc[i] = fma((double)xv.y, w1, acc[i]);
      acc[i] = fma((double)xv.z, w2, acc[i]);
      acc[i] = fma((double)xv.w, w3, acc[i]);
    }
  }

  float o[16];
  #pragma unroll
  for (int i = 0; i < 16; ++i) o[i] = (float)acc[i];

  // coalesced out writes + sq (same butterfly order as before)
  #pragma unroll
  for (int i = 0; i < 16; ++i){
    const int row = (w << 4) + i;                // local row 0..63
    out[((r0 + row) << 6) + c] = o[i];
    float ss = o[i] * o[i];
    #pragma unroll
    for (int off = 32; off; off >>= 1) ss += __shfl_xor(ss, off, 64);
    if (c == 0) sq32[r0 + row] = ss;
  }

  __syncthreads();                               // xs reads done; reuse as ldsT
  float* ldsT = xs;                              // [c][row] with pad 65
  #pragma unroll
  for (int i = 0; i < 16; ++i)
    ldsT[c * 65 + (w << 4) + i] = o[i];
  __syncthreads();

  // coalesced hT writes: wave w handles cols w, w+4, ..., lane = row
  float* hTg = hT32 + (((size_t)gb << 6) << 10);
  #pragma unroll
  for (int s = 0; s < 16; ++s){
    const int cc = w + (s << 2);
    hTg[((size_t)cc << 10) + lr0 + c] = ldsT[cc * 65 + c];
  }
}

// Block = 4 rows of graph gb (acc[4][4] => no spills). Phase A: f32 scores
// -> u32 keys in sv[4][1024]. Phase B: wave w owns row i0+w: top-24 u32
// selection, exact f64 re-score of candidates from f32 h, top-16 on u64 keys.
__global__ __launch_bounds__(256, 4) void edges_v4(
    const float* __restrict__ out32, const float* __restrict__ hT32,
    const float* __restrict__ sq32, const float* __restrict__ temp,
    float* __restrict__ rows_out, float* __restrict__ cols_out){
  __shared__ __align__(16) float hi[4][64];     // 1 KB
  __shared__ unsigned int sv[4][1024];          // 16 KB
  const int tid = threadIdx.x, wave = tid >> 6, lane = tid & 63;
  const int gb = blockIdx.x >> 8;
  const int i0 = (blockIdx.x & 255) << 2;

  ((float*)hi)[tid] = out32[((((size_t)gb << 10) + i0) << 6) + tid];
  __syncthreads();

  const float  Tf = temp[0];
  const double Td = (double)temp[0];
  const float* hTg = hT32 + ((size_t)gb << 16);
  const float* sqg = sq32 + ((size_t)gb << 10);

  float sqjv[4], sqiv[4];
  #pragma unroll
  for (int jj = 0; jj < 4; ++jj) sqjv[jj] = sqg[(jj << 8) + tid];
  #pragma unroll
  for (int r = 0; r < 4; ++r) sqiv[r] = sqg[i0 + r];

  float acc[4][4];
  #pragma unroll
  for (int r = 0; r < 4; ++r)
    #pragma unroll
    for (int jj = 0; jj < 4; ++jj) acc[r][jj] = 0.0f;

  #pragma unroll 1
  for (int q = 0; q < 64; q += 4){
    float4 a[4];
    #pragma unroll
    for (int r = 0; r < 4; ++r) a[r] = *(const float4*)&hi[r][q];
    const float* col = hTg + ((size_t)q << 10) + tid;
    #pragma unroll
    for (int jj = 0; jj < 4; ++jj){
      float b0 = col[(jj << 8)];
      float b1 = col[(jj << 8) + 1024];
      float b2 = col[(jj << 8) + 2048];
      float b3 = col[(jj << 8) + 3072];
      #pragma unroll
      for (int r = 0; r < 4; ++r)
        acc[r][jj] = fmaf(a[r].x, b0, fmaf(a[r].y, b1,
                     fmaf(a[r].z, b2, fmaf(a[r].w, b3, acc[r][jj]))));
    }
  }

  const float T2f = Tf + Tf;
  #pragma unroll
  for (int r = 0; r < 4; ++r){
    const float tsi = Tf * sqiv[r];
    #pragma unroll
    for (int jj = 0; jj < 4; ++jj){
      const int j = (jj << 8) + tid;
      float arg = fmaf(T2f, acc[r][jj], -fmaf(Tf, sqjv[jj], tsi));
      float sgm = __expf(arg);
      unsigned int e = ((unsigned int)gb << 20) |
                       ((unsigned int)(i0 + r) << 10) | (unsigned int)j;
      unsigned int bits = tf_bits_part(e);
      float uf = __uint_as_float(0x3f800000u | (bits >> 9)) - 1.0f;
      uf = (uf > 0.0f) ? uf : 1.17549435e-38f;
      float z = -__logf(-__logf(uf));
      float s = sgm + z;
      unsigned int kb = __float_as_uint(s);
      kb ^= (unsigned int)(((int)kb) >> 31) | 0x80000000u;
      kb = (kb & ~1023u) | (unsigned int)(1023 - j);
      sv[r][j] = kb;
    }
  }
  __syncthreads();

  { // wave owns row i0 + wave
    const int r = wave;
    const int grow = (gb << 10) + i0 + r;
    unsigned int v[16];
    #pragma unroll
    for (int m = 0; m < 16; ++m) v[m] = sv[r][(m << 6) + lane];
    unsigned int lm = v[0];
    #pragma unroll
    for (int m = 1; m < 16; ++m) lm = (v[m] > lm) ? v[m] : lm;

    int myj = 0;
    #pragma unroll 1
    for (int c = 0; c < 24; ++c){
      unsigned int best = lm;
      #pragma unroll
      for (int off = 32; off; off >>= 1){
        unsigned int o = __shfl_xor(best, off, 64);
        best = (o > best) ? o : best;
      }
      const int bj = 1023 - (int)(best & 1023u);
      if (c == lane) myj = bj;
      if ((bj & 63) == lane){
        unsigned int nm = 0u;
        #pragma unroll
        for (int m = 0; m < 16; ++m){
          v[m] = (v[m] == best) ? 0u : v[m];
          nm = (v[m] > nm) ? v[m] : nm;
        }
        lm = nm;
      }
    }

    // exact f64 re-score of 24 candidates from f32-rounded h
    const float* og = out32 + ((size_t)gb << 16);
    const double hiv = (double)og[((size_t)(i0 + r) << 6) + lane];
    double darg = 0.0;
    #pragma unroll 1
    for (int c = 0; c < 24; ++c){
      int jc = __shfl(myj, c, 64);
      double d = hiv - (double)og[((size_t)jc << 6) + lane];
      double p = d * d;
      #pragma unroll
      for (int off = 32; off; off >>= 1) p += __shfl_xor(p, off, 64);
      if (lane == c) darg = p;
    }
    unsigned long long key = 0ull;
    if (lane < 24){
      double sgm = fast_exp(-Td * darg);
      unsigned int e = ((unsigned int)gb << 20) |
                       ((unsigned int)(i0 + r) << 10) | (unsigned int)myj;
      unsigned int bits = tf_bits_part(e);
      float f = __uint_as_float(0x3f800000u | (bits >> 9)) - 1.0f;
      double u = (f > 0.0f) ? (double)f : 1.1754943508222875e-38;
      double w = -fast_log(u);
      double z = -fast_log(w);
      double s = sgm + z;
      unsigned long long kb = (unsigned long long)__double_as_longlong(s);
      kb ^= (unsigned long long)(((long long)kb) >> 63) |
            0x8000000000000000ull;
      key = (kb & ~1023ull) | (unsigned long long)(1023 - myj);
    }
    float* rowp = rows_out + ((size_t)grow << 4);
    float* colp = cols_out + ((size_t)grow << 4);
    if (lane < 16) rowp[lane] = (float)grow;
    #pragma unroll 1
    for (int k = 0; k < 16; ++k){
      unsigned long long best = key;
      #pragma unroll
      for (int off = 32; off; off >>= 1){
        unsigned long long o = __shfl_xor(best, off, 64);
        best = (o > best) ? o : best;
      }
      if (lane == 0)
        colp[k] = (float)((gb << 10) + (1023 - (int)(best & 1023ull)));
      key = (key == best) ? 0ull : key;
    }
  }
}

// ---------------- proven fallback (tiny ws): full f64 from f32 h ----------------

__device__ __forceinline__ double gumbel_z_ref(unsigned int bits){
  float f = __uint_as_float(0x3f800000u | (bits >> 9)) - 1.0f;
  double u = (f > 0.0f) ? (double)f : 1.1754943508222875e-38;
  return -log(-log(u));
}

__global__ __launch_bounds__(256) void encoder_kernel(
    const float* __restrict__ x, const float* __restrict__ W,
    const float* __restrict__ b, float* __restrict__ out){
  __shared__ float xs[512];
  const int tid = threadIdx.x;
  const size_t row0 = (size_t)blockIdx.x << 2;
  ((float2*)xs)[tid] = ((const float2*)(x + (row0 << 7)))[tid];
  __syncthreads();
  const int c = tid & 63, r = tid >> 6;
  double acc = (double)b[c];
  const float* xr = xs + (r << 7);
  #pragma unroll 16
  for (int k = 0; k < 128; ++k)
    acc += (double)xr[k] * (double)W[(k << 6) + c];
  out[((row0 + (size_t)r) << 6) + c] = (float)acc;
}

__global__ __launch_bounds__(256) void edges_kernel(
    const float* __restrict__ h, const float* __restrict__ temp,
    float* __restrict__ rows_out, float* __restrict__ cols_out){
  __shared__ double hi[4][64];
  __shared__ double sv[4][1024];
  const int tid = threadIdx.x;
  const int gb = blockIdx.x >> 8;
  const int i0 = (blockIdx.x & 255) << 2;
  const float* __restrict__ hbase = h + ((size_t)gb << 16);

  hi[tid >> 6][tid & 63] = (double)hbase[((size_t)i0 << 6) + tid];
  __syncthreads();

  const double Tmp = (double)temp[0];
  double acc[4][4];
  #pragma unroll
  for (int r = 0; r < 4; ++r)
    #pragma unroll
    for (int jj = 0; jj < 4; ++jj) acc[r][jj] = 0.0;

  #pragma unroll 1
  for (int jj = 0; jj < 4; ++jj){
    const float* __restrict__ hjr = hbase + (((size_t)(jj << 8) + tid) << 6);
    #pragma unroll 8
    for (int q = 0; q < 64; ++q){
      double bq = (double)hjr[q];
      #pragma unroll
      for (int r = 0; r < 4; ++r){
        double d = hi[r][q] - bq;
        acc[r][jj] = fma(d, d, acc[r][jj]);
      }
    }
  }

  #pragma unroll
  for (int r = 0; r < 4; ++r){
    #pragma unroll
    for (int jj = 0; jj < 4; ++jj){
      int j = (jj << 8) + tid;
      unsigned int e = ((unsigned int)gb << 20) |
                       ((unsigned int)(i0 + r) << 10) | (unsigned int)j;
      unsigned int bits = tf_bits_part(e);
      sv[r][j] = exp(-Tmp * acc[r][jj]) + gumbel_z_ref(bits);
    }
  }
  __syncthreads();

  const int wave = tid >> 6, lane = tid & 63;
  double v[16];
  #pragma unroll
  for (int m = 0; m < 16; ++m) v[m] = sv[wave][(m << 6) + lane];

  const int grow = (gb << 10) + i0 + wave;
  float* rowp = rows_out + ((size_t)grow << 4);
  float* colp = cols_out + ((size_t)grow << 4);
  if (lane < 16) rowp[lane] = (float)grow;

  #pragma unroll 1
  for (int k = 0; k < 16; ++k){
    double bv = -1.0e308; int bj = 1 << 30;
    #pragma unroll
    for (int m = 0; m < 16; ++m){
      int j = (m << 6) + lane;
      bool better = (v[m] > bv) || (v[m] == bv && j < bj);
      if (better){ bv = v[m]; bj = j; }
    }
    #pragma unroll
    for (int off = 32; off; off >>= 1){
      double ov = __shfl_xor(bv, off, 64);
      int    oj = __shfl_xor(bj, off, 64);
      bool better = (ov > bv) || (ov == bv && oj < bj);
      if (better){ bv = ov; bj = oj; }
    }
    if ((bj & 63) == lane) v[bj >> 6] = -1.0e308;
    if (lane == 0) colp[k] = (float)((gb << 10) + bj);
  }
}

extern "C" void kernel_launch(void* const* d_in, const int* in_sizes, int n_in,
                              void* d_out, int out_size, void* d_ws, size_t ws_size,
                              hipStream_t stream){
  const float* x = (const float*)d_in[0];
  const float* W = (const float*)d_in[1];
  const float* b = (const float*)d_in[2];
  const float* T = (const float*)d_in[3];
  float* out      = (float*)d_out;
  float* rows_out = out + OUT_ELEMS;
  float* cols_out = rows_out + EDGE_ELEMS;

  if (ws_size >= WS_NEED){
    float* hT32 = (float*)d_ws;
    float* sq32 = (float*)((char*)d_ws + HT32_BYTES);
    encoder_v4<<<512, 256, 0, stream>>>(x, W, b, out, hT32, sq32);
    edges_v4<<<8192, 256, 0, stream>>>(out, hT32, sq32, T, rows_out, cols_out);
  } else {
    encoder_kernel<<<8192, 256, 0, stream>>>(x, W, b, out);
    edges_kernel<<<8192, 256, 0, stream>>>(out, T, rows_out, cols_out);
  }
}

// Round 8
// 349.347 us; speedup vs baseline: 2.2266x; 1.0684x over previous
//
#include <hip/hip_runtime.h>
#include <math.h>

// B=32 graphs, N=1024 nodes, D=128 in-dim, C=64 out-dim, K=16.
#define OUT_ELEMS 2097152   // 32768*64
#define EDGE_ELEMS 524288   // 32*1024*16
#define HT32_BYTES (32768ull * 64ull * 4ull)   // 8 MiB f32 hT4 [16][1024][4] per graph
#define SQ32_BYTES (32768ull * 4ull)           // 128 KiB f32 row norms
#define WS_NEED (HT32_BYTES + SQ32_BYTES)
#define NCAND 20

__device__ __forceinline__ unsigned int rotl32(unsigned int x, int r){
  return (x << r) | (x >> (32 - r));
}

// JAX partitionable threefry, key (0,1): counter = (0, e); out = o0 ^ o1.
__device__ __forceinline__ unsigned int tf_bits_part(unsigned int e){
  unsigned int x0 = 0u, x1 = e;
  const unsigned int ks1 = 1u;
  const unsigned int ks2 = 0x1BD11BDBu;
  x1 += ks1;
#define TFR(r) { x0 += x1; x1 = rotl32(x1, r); x1 ^= x0; }
  TFR(13) TFR(15) TFR(26) TFR(6)
  x0 += ks1; x1 += ks2 + 1u;
  TFR(17) TFR(29) TFR(16) TFR(24)
  x0 += ks2; x1 += 0u + 2u;
  TFR(13) TFR(15) TFR(26) TFR(6)
  x0 += 0u;  x1 += ks1 + 3u;
  TFR(17) TFR(29) TFR(16) TFR(24)
  x0 += ks1; x1 += ks2 + 4u;
  TFR(13) TFR(15) TFR(26) TFR(6)
  x0 += ks2; x1 += 0u + 5u;
#undef TFR
  return x0 ^ x1;
}

// hardware f64 reciprocal + 2 Newton steps: rel err ~1e-16.
__device__ __forceinline__ double rcp64(double x){
  double r;
  asm("v_rcp_f64 %0, %1" : "=v"(r) : "v"(x));
  double e = fma(-x, r, 1.0); r = fma(r, e, r);
  e = fma(-x, r, 1.0); r = fma(r, e, r);
  return r;
}

// fast e^x for x in [-740, ~1]; rel err ~2e-11 (deg-9).
__device__ __forceinline__ double fast_exp(double x){
  double fn = __builtin_rint(x * 1.4426950408889634);
  int n = (int)fn;
  double r = fma(fn, -0.6931471803691238, x);
  r = fma(fn, -1.9082149292705877e-10, r);
  double p = 2.7557319223985893e-06;
  p = fma(r, p, 2.4801587301587302e-05);
  p = fma(r, p, 1.9841269841269841e-04);
  p = fma(r, p, 1.3888888888888889e-03);
  p = fma(r, p, 8.3333333333333333e-03);
  p = fma(r, p, 4.1666666666666664e-02);
  p = fma(r, p, 1.6666666666666666e-01);
  p = fma(r, p, 0.5);
  p = fma(r, p, 1.0);
  p = fma(r, p, 1.0);
  double scale = __longlong_as_double(((long long)(n + 1023)) << 52);
  return p * scale;
}

// fast ln(x), normal positive x; atanh form; abs err ~2e-11.
__device__ __forceinline__ double fast_log(double x){
  long long bx = __double_as_longlong(x);
  long long e = (bx >> 52) - 1023;
  double m = __longlong_as_double((bx & 0xFFFFFFFFFFFFFll) |
                                  0x3FF0000000000000ll);
  int big = m > 1.4142135623730951;
  m = big ? 0.5 * m : m;
  e += big;
  double s = (m - 1.0) * rcp64(m + 1.0);
  double s2 = s * s;
  double p = fma(s2, 2.0/11.0, 2.0/9.0);
  p = fma(s2, p, 2.0/7.0);
  p = fma(s2, p, 2.0/5.0);
  p = fma(s2, p, 2.0/3.0);
  double lm = fma(s * s2, p, 2.0 * s);
  return fma((double)e, 0.6931471805599453, lm);
}

// ---------------- fast path ----------------

// Block = 64 rows of one graph. W read from global (L2-resident) so LDS is
// only the x tile (32 KB -> 4-5 blocks/CU). f64 k-sequential accumulation
// (bit-identical out), sq butterfly in original lane order, LDS-staged
// transpose producing hT4 interleaved layout [qg][j][4].
__global__ __launch_bounds__(256) void encoder_v5(
    const float* __restrict__ x, const float* __restrict__ W,
    const float* __restrict__ b, float* __restrict__ out,
    float* __restrict__ hT4, float* __restrict__ sq32){
  __shared__ float xs[8192];   // 64 rows x 128 (reused as ldsT[64][65])
  const int tid = threadIdx.x;
  const int w = tid >> 6, c = tid & 63;
  const size_t r0 = (size_t)blockIdx.x << 6;     // 64 rows per block
  const int gb = (int)(r0 >> 10);
  const int lr0 = (int)(r0 & 1023);

  { // stage x tile (coalesced float4)
    const float4* xg4 = (const float4*)(x + (r0 << 7));
    float4* xs4 = (float4*)xs;
    #pragma unroll
    for (int s = 0; s < 8; ++s)
      xs4[tid + (s << 8)] = xg4[tid + (s << 8)];
  }
  __syncthreads();

  // wave w computes rows w*16..w*16+15, column c (f64, k-sequential)
  double acc[16];
  const double bc = (double)b[c];
  #pragma unroll
  for (int i = 0; i < 16; ++i) acc[i] = bc;

  #pragma unroll 4
  for (int k = 0; k < 128; k += 4){
    const double w0 = (double)W[((k + 0) << 6) + c];
    const double w1 = (double)W[((k + 1) << 6) + c];
    const double w2 = (double)W[((k + 2) << 6) + c];
    const double w3 = (double)W[((k + 3) << 6) + c];
    #pragma unroll
    for (int i = 0; i < 16; ++i){
      const float4 xv = *(const float4*)&xs[(((w << 4) + i) << 7) + k];
      acc[i] = fma((double)xv.x, w0, acc[i]);
      acc[i] = fma((double)xv.y, w1, acc[i]);
      acc[i] = fma((double)xv.z, w2, acc[i]);
      acc[i] = fma((double)xv.w, w3, acc[i]);
    }
  }

  float o[16];
  #pragma unroll
  for (int i = 0; i < 16; ++i) o[i] = (float)acc[i];

  #pragma unroll
  for (int i = 0; i < 16; ++i){
    const int row = (w << 4) + i;                // local row 0..63
    out[((r0 + row) << 6) + c] = o[i];
    float ss = o[i] * o[i];
    #pragma unroll
    for (int off = 32; off; off >>= 1) ss += __shfl_xor(ss, off, 64);
    if (c == 0) sq32[r0 + row] = ss;
  }

  __syncthreads();                               // xs reads done; reuse as ldsT
  float* ldsT = xs;                              // [dim][row] with pad 65
  #pragma unroll
  for (int i = 0; i < 16; ++i)
    ldsT[c * 65 + (w << 4) + i] = o[i];
  __syncthreads();

  // hT4 writes: wave w handles dim-groups qg = w, w+4, w+8, w+12; lane = row.
  float* hTg = hT4 + ((size_t)gb << 16);
  #pragma unroll
  for (int s = 0; s < 4; ++s){
    const int qg = w + (s << 2);
    float4 v;
    v.x = ldsT[((qg << 2) + 0) * 65 + c];
    v.y = ldsT[((qg << 2) + 1) * 65 + c];
    v.z = ldsT[((qg << 2) + 2) * 65 + c];
    v.w = ldsT[((qg << 2) + 3) * 65 + c];
    *(float4*)(hTg + ((size_t)qg << 12) + (((size_t)lr0 + c) << 2)) = v;
  }
}

// Block = 4 rows of graph gb. Phase A: f32 scores -> u32 keys (index in low
// 10 bits), packed uint4 into LDS. Phase B per wave (one row): top-20 u32
// extraction, exact f64 re-score of candidates from f32-rounded h, final
// top-16 via 32-lane bitonic sort on exact u64 keys, coalesced writes.
__global__ __launch_bounds__(256, 4) void edges_v5(
    const float* __restrict__ out32, const float* __restrict__ hT4,
    const float* __restrict__ sq32, const float* __restrict__ temp,
    float* __restrict__ rows_out, float* __restrict__ cols_out){
  __shared__ __align__(16) float hi[4][64];        // 1 KB
  __shared__ __align__(16) unsigned int sv[4][1024]; // 16 KB
  const int tid = threadIdx.x, wave = tid >> 6, lane = tid & 63;
  const int gb = blockIdx.x >> 8;
  const int i0 = (blockIdx.x & 255) << 2;

  ((float*)hi)[tid] = out32[((((size_t)gb << 10) + i0) << 6) + tid];
  __syncthreads();

  const float  Tf = temp[0];
  const double Td = (double)temp[0];
  const float* hTg = hT4 + ((size_t)gb << 16);
  const float* sqg = sq32 + ((size_t)gb << 10);

  float sqjv[4], sqiv[4];
  #pragma unroll
  for (int jj = 0; jj < 4; ++jj) sqjv[jj] = sqg[(jj << 8) + tid];
  #pragma unroll
  for (int r = 0; r < 4; ++r) sqiv[r] = sqg[i0 + r];

  float acc[4][4];
  #pragma unroll
  for (int r = 0; r < 4; ++r)
    #pragma unroll
    for (int jj = 0; jj < 4; ++jj) acc[r][jj] = 0.0f;

  #pragma unroll 1
  for (int qg = 0; qg < 16; ++qg){
    float4 a[4];
    #pragma unroll
    for (int r = 0; r < 4; ++r) a[r] = *(const float4*)&hi[r][qg << 2];
    const float4* colq = (const float4*)(hTg + ((size_t)qg << 12));
    #pragma unroll
    for (int jj = 0; jj < 4; ++jj){
      float4 b4 = colq[(jj << 8) + tid];
      #pragma unroll
      for (int r = 0; r < 4; ++r)
        acc[r][jj] = fmaf(a[r].x, b4.x, fmaf(a[r].y, b4.y,
                     fmaf(a[r].z, b4.z, fmaf(a[r].w, b4.w, acc[r][jj]))));
    }
  }

  const float T2f = Tf + Tf;
  #pragma unroll
  for (int r = 0; r < 4; ++r){
    const float tsi = Tf * sqiv[r];
    unsigned int kv[4];
    #pragma unroll
    for (int jj = 0; jj < 4; ++jj){
      const int j = (jj << 8) + tid;
      float arg = fmaf(T2f, acc[r][jj], -fmaf(Tf, sqjv[jj], tsi));
      float sgm = __expf(arg);
      unsigned int e = ((unsigned int)gb << 20) |
                       ((unsigned int)(i0 + r) << 10) | (unsigned int)j;
      unsigned int bits = tf_bits_part(e);
      float uf = __uint_as_float(0x3f800000u | (bits >> 9)) - 1.0f;
      uf = (uf > 0.0f) ? uf : 1.17549435e-38f;
      float z = -__logf(-__logf(uf));
      float s = sgm + z;
      unsigned int kb = __float_as_uint(s);
      kb ^= (unsigned int)(((int)kb) >> 31) | 0x80000000u;
      kv[jj] = (kb & ~1023u) | (unsigned int)(1023 - j);
    }
    *(uint4*)&sv[r][tid << 2] = make_uint4(kv[0], kv[1], kv[2], kv[3]);
  }
  __syncthreads();

  { // wave owns row i0 + wave
    const int r = wave;
    const int grow = (gb << 10) + i0 + r;
    unsigned int v[16];
    #pragma unroll
    for (int g = 0; g < 4; ++g){
      uint4 t = *(const uint4*)&sv[r][(g << 8) + (lane << 2)];
      v[(g << 2) + 0] = t.x; v[(g << 2) + 1] = t.y;
      v[(g << 2) + 2] = t.z; v[(g << 2) + 3] = t.w;
    }
    unsigned int lm = v[0];
    #pragma unroll
    for (int m = 1; m < 16; ++m) lm = (v[m] > lm) ? v[m] : lm;

    int myj = 0;
    #pragma unroll 1
    for (int c = 0; c < NCAND; ++c){
      unsigned int best = lm;
      #pragma unroll
      for (int off = 32; off; off >>= 1){
        unsigned int o = __shfl_xor(best, off, 64);
        best = (o > best) ? o : best;
      }
      const int bj = 1023 - (int)(best & 1023u);
      if (c == lane) myj = bj;
      if ((bj & 63) == lane){
        unsigned int nm = 0u;
        #pragma unroll
        for (int m = 0; m < 16; ++m){
          v[m] = (v[m] == best) ? 0u : v[m];
          nm = (v[m] > nm) ? v[m] : nm;
        }
        lm = nm;
      }
    }

    // exact f64 re-score of NCAND candidates from f32-rounded h
    const float* og = out32 + ((size_t)gb << 16);
    const double hiv = (double)og[((size_t)(i0 + r) << 6) + lane];
    double darg = 0.0;
    #pragma unroll 1
    for (int c = 0; c < NCAND; ++c){
      int jc = __shfl(myj, c, 64);
      double d = hiv - (double)og[((size_t)jc << 6) + lane];
      double p = d * d;
      #pragma unroll
      for (int off = 32; off; off >>= 1) p += __shfl_xor(p, off, 64);
      if (lane == c) darg = p;
    }
    unsigned long long key = 0ull;
    if (lane < NCAND){
      double sgm = fast_exp(-Td * darg);
      unsigned int e = ((unsigned int)gb << 20) |
                       ((unsigned int)(i0 + r) << 10) | (unsigned int)myj;
      unsigned int bits = tf_bits_part(e);
      float f = __uint_as_float(0x3f800000u | (bits >> 9)) - 1.0f;
      double u = (f > 0.0f) ? (double)f : 1.1754943508222875e-38;
      double w = -fast_log(u);
      double z = -fast_log(w);
      double s = sgm + z;
      unsigned long long kb = (unsigned long long)__double_as_longlong(s);
      kb ^= (unsigned long long)(((long long)kb) >> 63) |
            0x8000000000000000ull;
      key = (kb & ~1023ull) | (unsigned long long)(1023 - myj);
    }

    // bitonic sort, descending over lanes 0..31 (lanes 32-63 hold 0)
    #pragma unroll
    for (int k = 2; k <= 32; k <<= 1){
      #pragma unroll
      for (int j = k >> 1; j > 0; j >>= 1){
        unsigned long long other = __shfl_xor(key, j, 64);
        bool keep_hi = (((lane & k) == 0) == ((lane & j) == 0));
        key = (keep_hi == (other > key)) ? other : key;
      }
    }

    float* rowp = rows_out + ((size_t)grow << 4);
    float* colp = cols_out + ((size_t)grow << 4);
    if (lane < 16){
      rowp[lane] = (float)grow;
      colp[lane] = (float)((gb << 10) + (1023 - (int)(key & 1023ull)));
    }
  }
}

// ---------------- proven fallback (tiny ws): full f64 from f32 h ----------------

__device__ __forceinline__ double gumbel_z_ref(unsigned int bits){
  float f = __uint_as_float(0x3f800000u | (bits >> 9)) - 1.0f;
  double u = (f > 0.0f) ? (double)f : 1.1754943508222875e-38;
  return -log(-log(u));
}

__global__ __launch_bounds__(256) void encoder_kernel(
    const float* __restrict__ x, const float* __restrict__ W,
    const float* __restrict__ b, float* __restrict__ out){
  __shared__ float xs[512];
  const int tid = threadIdx.x;
  const size_t row0 = (size_t)blockIdx.x << 2;
  ((float2*)xs)[tid] = ((const float2*)(x + (row0 << 7)))[tid];
  __syncthreads();
  const int c = tid & 63, r = tid >> 6;
  double acc = (double)b[c];
  const float* xr = xs + (r << 7);
  #pragma unroll 16
  for (int k = 0; k < 128; ++k)
    acc += (double)xr[k] * (double)W[(k << 6) + c];
  out[((row0 + (size_t)r) << 6) + c] = (float)acc;
}

__global__ __launch_bounds__(256) void edges_kernel(
    const float* __restrict__ h, const float* __restrict__ temp,
    float* __restrict__ rows_out, float* __restrict__ cols_out){
  __shared__ double hi[4][64];
  __shared__ double sv[4][1024];
  const int tid = threadIdx.x;
  const int gb = blockIdx.x >> 8;
  const int i0 = (blockIdx.x & 255) << 2;
  const float* __restrict__ hbase = h + ((size_t)gb << 16);

  hi[tid >> 6][tid & 63] = (double)hbase[((size_t)i0 << 6) + tid];
  __syncthreads();

  const double Tmp = (double)temp[0];
  double acc[4][4];
  #pragma unroll
  for (int r = 0; r < 4; ++r)
    #pragma unroll
    for (int jj = 0; jj < 4; ++jj) acc[r][jj] = 0.0;

  #pragma unroll 1
  for (int jj = 0; jj < 4; ++jj){
    const float* __restrict__ hjr = hbase + (((size_t)(jj << 8) + tid) << 6);
    #pragma unroll 8
    for (int q = 0; q < 64; ++q){
      double bq = (double)hjr[q];
      #pragma unroll
      for (int r = 0; r < 4; ++r){
        double d = hi[r][q] - bq;
        acc[r][jj] = fma(d, d, acc[r][jj]);
      }
    }
  }

  #pragma unroll
  for (int r = 0; r < 4; ++r){
    #pragma unroll
    for (int jj = 0; jj < 4; ++jj){
      int j = (jj << 8) + tid;
      unsigned int e = ((unsigned int)gb << 20) |
                       ((unsigned int)(i0 + r) << 10) | (unsigned int)j;
      unsigned int bits = tf_bits_part(e);
      sv[r][j] = exp(-Tmp * acc[r][jj]) + gumbel_z_ref(bits);
    }
  }
  __syncthreads();

  const int wave = tid >> 6, lane = tid & 63;
  double v[16];
  #pragma unroll
  for (int m = 0; m < 16; ++m) v[m] = sv[wave][(m << 6) + lane];

  const int grow = (gb << 10) + i0 + wave;
  float* rowp = rows_out + ((size_t)grow << 4);
  float* colp = cols_out + ((size_t)grow << 4);
  if (lane < 16) rowp[lane] = (float)grow;

  #pragma unroll 1
  for (int k = 0; k < 16; ++k){
    double bv = -1.0e308; int bj = 1 << 30;
    #pragma unroll
    for (int m = 0; m < 16; ++m){
      int j = (m << 6) + lane;
      bool better = (v[m] > bv) || (v[m] == bv && j < bj);
      if (better){ bv = v[m]; bj = j; }
    }
    #pragma unroll
    for (int off = 32; off; off >>= 1){
      double ov = __shfl_xor(bv, off, 64);
      int    oj = __shfl_xor(bj, off, 64);
      bool better = (ov > bv) || (ov == bv && oj < bj);
      if (better){ bv = ov; bj = oj; }
    }
    if ((bj & 63) == lane) v[bj >> 6] = -1.0e308;
    if (lane == 0) colp[k] = (float)((gb << 10) + bj);
  }
}

extern "C" void kernel_launch(void* const* d_in, const int* in_sizes, int n_in,
                              void* d_out, int out_size, void* d_ws, size_t ws_size,
                              hipStream_t stream){
  const float* x = (const float*)d_in[0];
  const float* W = (const float*)d_in[1];
  const float* b = (const float*)d_in[2];
  const float* T = (const float*)d_in[3];
  float* out      = (float*)d_out;
  float* rows_out = out + OUT_ELEMS;
  float* cols_out = rows_out + EDGE_ELEMS;

  if (ws_size >= WS_NEED){
    float* hT4  = (float*)d_ws;
    float* sq32 = (float*)((char*)d_ws + HT32_BYTES);
    encoder_v5<<<512, 256, 0, stream>>>(x, W, b, out, hT4, sq32);
    edges_v5<<<8192, 256, 0, stream>>>(out, hT4, sq32, T, rows_out, cols_out);
  } else {
    encoder_kernel<<<8192, 256, 0, stream>>>(x, W, b, out);
    edges_kernel<<<8192, 256, 0, stream>>>(out, T, rows_out, cols_out);
  }
}

// Round 9
// 254.828 us; speedup vs baseline: 3.0525x; 1.3709x over previous
//
#include <hip/hip_runtime.h>
#include <math.h>

// B=32 graphs, N=1024 nodes, D=128 in-dim, C=64 out-dim, K=16.
#define OUT_ELEMS 2097152   // 32768*64
#define EDGE_ELEMS 524288   // 32*1024*16

__device__ __forceinline__ unsigned int rotl32(unsigned int x, int r){
  return (x << r) | (x >> (32 - r));
}

// JAX partitionable threefry, key (0,1): counter = (0, e); out = o0 ^ o1.
__device__ __forceinline__ unsigned int tf_bits_part(unsigned int e){
  unsigned int x0 = 0u, x1 = e;
  const unsigned int ks1 = 1u;
  const unsigned int ks2 = 0x1BD11BDBu;
  x1 += ks1;
#define TFR(r) { x0 += x1; x1 = rotl32(x1, r); x1 ^= x0; }
  TFR(13) TFR(15) TFR(26) TFR(6)
  x0 += ks1; x1 += ks2 + 1u;
  TFR(17) TFR(29) TFR(16) TFR(24)
  x0 += ks2; x1 += 0u + 2u;
  TFR(13) TFR(15) TFR(26) TFR(6)
  x0 += 0u;  x1 += ks1 + 3u;
  TFR(17) TFR(29) TFR(16) TFR(24)
  x0 += ks1; x1 += ks2 + 4u;
  TFR(13) TFR(15) TFR(26) TFR(6)
  x0 += ks2; x1 += 0u + 5u;
#undef TFR
  return x0 ^ x1;
}

// hardware f64 reciprocal + 2 Newton steps: rel err ~1e-16.
__device__ __forceinline__ double rcp64(double x){
  double r;
  asm("v_rcp_f64 %0, %1" : "=v"(r) : "v"(x));
  double e = fma(-x, r, 1.0); r = fma(r, e, r);
  e = fma(-x, r, 1.0); r = fma(r, e, r);
  return r;
}

// fast e^x for x in [-740, ~1]; rel err ~2e-11 (deg-9).
__device__ __forceinline__ double fast_exp(double x){
  double fn = __builtin_rint(x * 1.4426950408889634);
  int n = (int)fn;
  double r = fma(fn, -0.6931471803691238, x);
  r = fma(fn, -1.9082149292705877e-10, r);
  double p = 2.7557319223985893e-06;
  p = fma(r, p, 2.4801587301587302e-05);
  p = fma(r, p, 1.9841269841269841e-04);
  p = fma(r, p, 1.3888888888888889e-03);
  p = fma(r, p, 8.3333333333333333e-03);
  p = fma(r, p, 4.1666666666666664e-02);
  p = fma(r, p, 1.6666666666666666e-01);
  p = fma(r, p, 0.5);
  p = fma(r, p, 1.0);
  p = fma(r, p, 1.0);
  double scale = __longlong_as_double(((long long)(n + 1023)) << 52);
  return p * scale;
}

// fast ln(x), normal positive x; atanh form; abs err ~2e-11.
__device__ __forceinline__ double fast_log(double x){
  long long bx = __double_as_longlong(x);
  long long e = (bx >> 52) - 1023;
  double m = __longlong_as_double((bx & 0xFFFFFFFFFFFFFll) |
                                  0x3FF0000000000000ll);
  int big = m > 1.4142135623730951;
  m = big ? 0.5 * m : m;
  e += big;
  double s = (m - 1.0) * rcp64(m + 1.0);
  double s2 = s * s;
  double p = fma(s2, 2.0/11.0, 2.0/9.0);
  p = fma(s2, p, 2.0/7.0);
  p = fma(s2, p, 2.0/5.0);
  p = fma(s2, p, 2.0/3.0);
  double lm = fma(s * s2, p, 2.0 * s);
  return fma((double)e, 0.6931471805599453, lm);
}

// Exact f64 score of candidate jc for the row whose f64 h lives in hrow (LDS).
// Formulas bit-identical to the proven v5 rescore path.
__device__ __forceinline__ unsigned long long score_cand(
    const float* __restrict__ og, const double* __restrict__ hrow,
    unsigned int jc, unsigned int base, double Td, bool act){
  const float* cp4 = og + ((size_t)jc << 6);
  double acc = 0.0;
  #pragma unroll
  for (int ch = 0; ch < 4; ++ch){
    float cf[16];
    *(float4*)&cf[0]  = *(const float4*)(cp4 + (ch << 4));
    *(float4*)&cf[4]  = *(const float4*)(cp4 + (ch << 4) + 4);
    *(float4*)&cf[8]  = *(const float4*)(cp4 + (ch << 4) + 8);
    *(float4*)&cf[12] = *(const float4*)(cp4 + (ch << 4) + 12);
    #pragma unroll
    for (int q = 0; q < 16; ++q){
      double d = hrow[(ch << 4) + q] - (double)cf[q];
      acc = fma(d, d, acc);
    }
  }
  if (!act) return 0ull;
  double sgm = fast_exp(-Td * acc);
  unsigned int bits = tf_bits_part(base | jc);
  float f = __uint_as_float(0x3f800000u | (bits >> 9)) - 1.0f;
  double u = (f > 0.0f) ? (double)f : 1.1754943508222875e-38;
  double w = -fast_log(u);
  double z = -fast_log(w);
  double sc = sgm + z;
  unsigned long long kb = (unsigned long long)__double_as_longlong(sc);
  kb ^= (unsigned long long)(((long long)kb) >> 63) | 0x8000000000000000ull;
  return (kb & ~1023ull) | (unsigned long long)(1023u - jc);
}

// Full descending bitonic sort of u64 keys across 64 lanes.
__device__ __forceinline__ unsigned long long bitonic64_desc(
    unsigned long long key, int lane){
  #pragma unroll
  for (int k = 2; k <= 64; k <<= 1){
    #pragma unroll
    for (int j = k >> 1; j; j >>= 1){
      unsigned long long o = __shfl_xor(key, j, 64);
      bool keep_hi = ((lane & k) == 0) == ((lane & j) == 0);
      key = (keep_hi == (o > key)) ? o : key;
    }
  }
  return key;
}

// ---------------- encoder ----------------
// Block = 16 rows (2048 blocks). f64 k-sequential accumulation — bit-identical
// out vs all prior versions. No transpose / sq side outputs needed anymore.
__global__ __launch_bounds__(256) void encoder_v6(
    const float* __restrict__ x, const float* __restrict__ W,
    const float* __restrict__ b, float* __restrict__ out){
  __shared__ float xs[2048];    // 16 rows x 128
  const int tid = threadIdx.x;
  const int w = tid >> 6, c = tid & 63;
  const size_t r0 = (size_t)blockIdx.x << 4;
  const float4* xg4 = (const float4*)(x + (r0 << 7));
  float4* xs4 = (float4*)xs;
  xs4[tid] = xg4[tid];
  xs4[tid + 256] = xg4[tid + 256];
  __syncthreads();

  double acc[4];
  const double bc = (double)b[c];
  #pragma unroll
  for (int i = 0; i < 4; ++i) acc[i] = bc;

  #pragma unroll 4
  for (int k = 0; k < 128; k += 4){
    const double w0 = (double)W[((k + 0) << 6) + c];
    const double w1 = (double)W[((k + 1) << 6) + c];
    const double w2 = (double)W[((k + 2) << 6) + c];
    const double w3 = (double)W[((k + 3) << 6) + c];
    #pragma unroll
    for (int i = 0; i < 4; ++i){
      const float4 xv = *(const float4*)&xs[(((w << 2) + i) << 7) + k];
      acc[i] = fma((double)xv.x, w0, acc[i]);
      acc[i] = fma((double)xv.y, w1, acc[i]);
      acc[i] = fma((double)xv.z, w2, acc[i]);
      acc[i] = fma((double)xv.w, w3, acc[i]);
    }
  }
  #pragma unroll
  for (int i = 0; i < 4; ++i)
    out[((r0 + (w << 2) + i) << 6) + c] = (float)acc[i];
}

// ---------------- edges ----------------
// Block = 4 rows of graph gb; each wave fully owns one row (no __syncthreads).
// Phase 1: threefry bits for all 1024 j (index packed in low 10 bits).
// Phase 2: extract 16th-largest packed bits b16; conservative cut
//          c = bits(z(b16) - 1 - 1e-3)  (score <= z+1 since sigma <= 1).
// Phase 3: compact candidates (16 winners + all bits >= cut; avg ~44, cap 128).
// Phase 4: exact f64 scoring of candidates (formulas identical to v5 rescore),
//          64-lane bitonic sort on exact u64 keys, top-16 out.
__global__ __launch_bounds__(256) void edges_v6(
    const float* __restrict__ out32, const float* __restrict__ temp,
    float* __restrict__ rows_out, float* __restrict__ cols_out){
  __shared__ double hid[4][64];         // 2 KB
  __shared__ unsigned int cl[4][128];   // 2 KB
  const int tid = threadIdx.x, wave = tid >> 6, lane = tid & 63;
  const int gb = blockIdx.x >> 8;
  const int i0 = (blockIdx.x & 255) << 2;
  const int r  = i0 + wave;
  const float* __restrict__ og = out32 + ((size_t)gb << 16);

  hid[wave][lane] = (double)og[((size_t)r << 6) + lane];

  const unsigned int base = ((unsigned int)gb << 20) | ((unsigned int)r << 10);

  // Phase 1: bits for j = m*64 + lane
  unsigned int v[16];
  #pragma unroll
  for (int m = 0; m < 16; ++m){
    const unsigned int j = (unsigned int)(m << 6) + (unsigned int)lane;
    unsigned int bits = tf_bits_part(base | j);
    v[m] = (bits & ~1023u) | (1023u - j);   // low 10 bits don't feed u
  }

  // Phase 2: 16 extraction rounds (winner-lane invalidate + rescan)
  unsigned int lm = v[0];
  #pragma unroll
  for (int m = 1; m < 16; ++m) lm = (v[m] > lm) ? v[m] : lm;
  unsigned int b16p = 0;
  int winj = 0;
  #pragma unroll 1
  for (int k = 0; k < 16; ++k){
    unsigned int best = lm;
    #pragma unroll
    for (int off = 32; off; off >>= 1){
      unsigned int o = __shfl_xor(best, off, 64);
      best = (o > best) ? o : best;
    }
    b16p = best;
    const int bj = 1023 - (int)(best & 1023u);
    if (lane == k) winj = bj;
    if ((bj & 63) == lane){
      unsigned int nm = 0u;
      #pragma unroll
      for (int m = 0; m < 16; ++m){
        v[m] = (v[m] == best) ? 0u : v[m];
        nm = (v[m] > nm) ? v[m] : nm;
      }
      lm = nm;
    }
  }

  // conservative cut: keep j iff z_j >= z(b16) - 1 - margin
  float u16 = __uint_as_float(0x3f800000u | (b16p >> 9)) - 1.0f;
  float z16 = -__logf(-__logf(u16));
  float uc  = __expf(-__expf(-(z16 - 1.001f)));
  unsigned int cp = ((__float_as_uint(1.0f + uc) & 0x7FFFFFu) << 9) & ~1023u;

  // Phase 3: compaction — winners first, then survivors
  if (lane < 16) cl[wave][lane] = (unsigned int)winj;
  int cnt = 0;
  #pragma unroll
  for (int m = 0; m < 16; ++m) cnt += (v[m] >= cp) ? 1 : 0;
  int s = cnt;
  #pragma unroll
  for (int off = 1; off < 64; off <<= 1){
    int o = __shfl_up(s, off, 64);
    s += (lane >= off) ? o : 0;
  }
  int nc = 16 + __shfl(s, 63, 64);
  nc = (nc > 128) ? 128 : nc;
  int slot = 16 + (s - cnt);
  #pragma unroll
  for (int m = 0; m < 16; ++m){
    if (v[m] >= cp && slot < 128){
      cl[wave][slot] = 1023u - (v[m] & 1023u);
      ++slot;
    }
  }

  // Phase 4: exact scoring + sort
  const double Td = (double)temp[0];
  const bool act1 = (lane < nc);
  unsigned int jc1 = act1 ? cl[wave][lane] : 0u;
  unsigned long long key = score_cand(og, hid[wave], jc1, base, Td, act1);
  key = bitonic64_desc(key, lane);

  if (nc > 64){
    const int idx2 = 64 + lane;
    const bool act2 = (idx2 < nc);
    unsigned int jc2 = act2 ? cl[wave][idx2] : 0u;
    unsigned long long k2 = score_cand(og, hid[wave], jc2, base, Td, act2);
    k2 = bitonic64_desc(k2, lane);
    unsigned long long kr = __shfl(k2, 63 - lane, 64);
    key = (kr > key) ? kr : key;          // elementwise top-64 (bitonic)
    #pragma unroll
    for (int j = 32; j; j >>= 1){         // descending clean
      unsigned long long o = __shfl_xor(key, j, 64);
      bool left = (lane & j) == 0;
      bool take = left ? (o > key) : (o < key);
      key = take ? o : key;
    }
  }

  const int grow = (gb << 10) + r;
  if (lane < 16){
    rows_out[((size_t)grow << 4) + lane] = (float)grow;
    cols_out[((size_t)grow << 4) + lane] =
        (float)((gb << 10) + (1023 - (int)(key & 1023ull)));
  }
}

extern "C" void kernel_launch(void* const* d_in, const int* in_sizes, int n_in,
                              void* d_out, int out_size, void* d_ws, size_t ws_size,
                              hipStream_t stream){
  const float* x = (const float*)d_in[0];
  const float* W = (const float*)d_in[1];
  const float* b = (const float*)d_in[2];
  const float* T = (const float*)d_in[3];
  float* out      = (float*)d_out;
  float* rows_out = out + OUT_ELEMS;
  float* cols_out = rows_out + EDGE_ELEMS;

  encoder_v6<<<2048, 256, 0, stream>>>(x, W, b, out);
  edges_v6<<<8192, 256, 0, stream>>>(out, T, rows_out, cols_out);
}

// Round 10
// 214.891 us; speedup vs baseline: 3.6198x; 1.1858x over previous
//
#include <hip/hip_runtime.h>
#include <math.h>

// B=32 graphs, N=1024 nodes, D=128 in-dim, C=64 out-dim, K=16.
#define OUT_ELEMS 2097152   // 32768*64
#define EDGE_ELEMS 524288   // 32*1024*16

__device__ __forceinline__ unsigned int rotl32(unsigned int x, int r){
  return (x << r) | (x >> (32 - r));
}

// JAX partitionable threefry, key (0,1): counter = (0, e); out = o0 ^ o1.
__device__ __forceinline__ unsigned int tf_bits_part(unsigned int e){
  unsigned int x0 = 0u, x1 = e;
  const unsigned int ks1 = 1u;
  const unsigned int ks2 = 0x1BD11BDBu;
  x1 += ks1;
#define TFR(r) { x0 += x1; x1 = rotl32(x1, r); x1 ^= x0; }
  TFR(13) TFR(15) TFR(26) TFR(6)
  x0 += ks1; x1 += ks2 + 1u;
  TFR(17) TFR(29) TFR(16) TFR(24)
  x0 += ks2; x1 += 0u + 2u;
  TFR(13) TFR(15) TFR(26) TFR(6)
  x0 += 0u;  x1 += ks1 + 3u;
  TFR(17) TFR(29) TFR(16) TFR(24)
  x0 += ks1; x1 += ks2 + 4u;
  TFR(13) TFR(15) TFR(26) TFR(6)
  x0 += ks2; x1 += 0u + 5u;
#undef TFR
  return x0 ^ x1;
}

// hardware f64 reciprocal + 2 Newton steps: rel err ~1e-16.
__device__ __forceinline__ double rcp64(double x){
  double r;
  asm("v_rcp_f64 %0, %1" : "=v"(r) : "v"(x));
  double e = fma(-x, r, 1.0); r = fma(r, e, r);
  e = fma(-x, r, 1.0); r = fma(r, e, r);
  return r;
}

// fast e^x for x in [-740, ~1]; rel err ~2e-11 (deg-9).
__device__ __forceinline__ double fast_exp(double x){
  double fn = __builtin_rint(x * 1.4426950408889634);
  int n = (int)fn;
  double r = fma(fn, -0.6931471803691238, x);
  r = fma(fn, -1.9082149292705877e-10, r);
  double p = 2.7557319223985893e-06;
  p = fma(r, p, 2.4801587301587302e-05);
  p = fma(r, p, 1.9841269841269841e-04);
  p = fma(r, p, 1.3888888888888889e-03);
  p = fma(r, p, 8.3333333333333333e-03);
  p = fma(r, p, 4.1666666666666664e-02);
  p = fma(r, p, 1.6666666666666666e-01);
  p = fma(r, p, 0.5);
  p = fma(r, p, 1.0);
  p = fma(r, p, 1.0);
  double scale = __longlong_as_double(((long long)(n + 1023)) << 52);
  return p * scale;
}

// fast ln(x), normal positive x; atanh form; abs err ~2e-11.
__device__ __forceinline__ double fast_log(double x){
  long long bx = __double_as_longlong(x);
  long long e = (bx >> 52) - 1023;
  double m = __longlong_as_double((bx & 0xFFFFFFFFFFFFFll) |
                                  0x3FF0000000000000ll);
  int big = m > 1.4142135623730951;
  m = big ? 0.5 * m : m;
  e += big;
  double s = (m - 1.0) * rcp64(m + 1.0);
  double s2 = s * s;
  double p = fma(s2, 2.0/11.0, 2.0/9.0);
  p = fma(s2, p, 2.0/7.0);
  p = fma(s2, p, 2.0/5.0);
  p = fma(s2, p, 2.0/3.0);
  double lm = fma(s * s2, p, 2.0 * s);
  return fma((double)e, 0.6931471805599453, lm);
}

// Exact f64 score of candidate jc for the row whose f64 h lives in hrow (LDS).
// Formulas bit-identical to the proven v5/v6 rescore path.
__device__ __forceinline__ unsigned long long score_cand(
    const float* __restrict__ og, const double* __restrict__ hrow,
    unsigned int jc, unsigned int base, double Td, bool act){
  const float* cp4 = og + ((size_t)jc << 6);
  double acc = 0.0;
  #pragma unroll
  for (int ch = 0; ch < 4; ++ch){
    float cf[16];
    *(float4*)&cf[0]  = *(const float4*)(cp4 + (ch << 4));
    *(float4*)&cf[4]  = *(const float4*)(cp4 + (ch << 4) + 4);
    *(float4*)&cf[8]  = *(const float4*)(cp4 + (ch << 4) + 8);
    *(float4*)&cf[12] = *(const float4*)(cp4 + (ch << 4) + 12);
    #pragma unroll
    for (int q = 0; q < 16; ++q){
      double d = hrow[(ch << 4) + q] - (double)cf[q];
      acc = fma(d, d, acc);
    }
  }
  if (!act) return 0ull;
  double sgm = fast_exp(-Td * acc);
  unsigned int bits = tf_bits_part(base | jc);
  float f = __uint_as_float(0x3f800000u | (bits >> 9)) - 1.0f;
  double u = (f > 0.0f) ? (double)f : 1.1754943508222875e-38;
  double w = -fast_log(u);
  double z = -fast_log(w);
  double sc = sgm + z;
  unsigned long long kb = (unsigned long long)__double_as_longlong(sc);
  kb ^= (unsigned long long)(((long long)kb) >> 63) | 0x8000000000000000ull;
  return (kb & ~1023ull) | (unsigned long long)(1023u - jc);
}

// Full descending bitonic sort of u64 keys across 64 lanes.
__device__ __forceinline__ unsigned long long bitonic64_desc(
    unsigned long long key, int lane){
  #pragma unroll
  for (int k = 2; k <= 64; k <<= 1){
    #pragma unroll
    for (int j = k >> 1; j; j >>= 1){
      unsigned long long o = __shfl_xor(key, j, 64);
      bool keep_hi = ((lane & k) == 0) == ((lane & j) == 0);
      key = (keep_hi == (o > key)) ? o : key;
    }
  }
  return key;
}

// Full descending bitonic sort of u32 keys across 64 lanes.
__device__ __forceinline__ unsigned int bitonic32_desc(
    unsigned int key, int lane){
  #pragma unroll
  for (int k = 2; k <= 64; k <<= 1){
    #pragma unroll
    for (int j = k >> 1; j; j >>= 1){
      unsigned int o = __shfl_xor(key, j, 64);
      bool keep_hi = ((lane & k) == 0) == ((lane & j) == 0);
      key = (keep_hi == (o > key)) ? o : key;
    }
  }
  return key;
}

// ---------------- encoder ----------------
// Block = 16 rows (2048 blocks). x tile (8 KB) + W tile (32 KB) in LDS ->
// 4 blocks/CU. f64 k-sequential accumulation — bit-identical out vs all
// prior passing versions.
__global__ __launch_bounds__(256) void encoder_v7(
    const float* __restrict__ x, const float* __restrict__ W,
    const float* __restrict__ b, float* __restrict__ out){
  __shared__ float xs[2048];    // 16 rows x 128
  __shared__ float wsh[8192];   // 128 x 64
  const int tid = threadIdx.x;
  const int w = tid >> 6, c = tid & 63;
  const size_t r0 = (size_t)blockIdx.x << 4;
  const float4* xg4 = (const float4*)(x + (r0 << 7));
  float4* xs4 = (float4*)xs;
  xs4[tid] = xg4[tid];
  xs4[tid + 256] = xg4[tid + 256];
  const float4* wg4 = (const float4*)W;
  float4* ws4 = (float4*)wsh;
  #pragma unroll
  for (int sx = 0; sx < 8; ++sx)
    ws4[tid + (sx << 8)] = wg4[tid + (sx << 8)];
  __syncthreads();

  double acc[4];
  const double bc = (double)b[c];
  #pragma unroll
  for (int i = 0; i < 4; ++i) acc[i] = bc;

  #pragma unroll 4
  for (int k = 0; k < 128; k += 4){
    const double w0 = (double)wsh[((k + 0) << 6) + c];
    const double w1 = (double)wsh[((k + 1) << 6) + c];
    const double w2 = (double)wsh[((k + 2) << 6) + c];
    const double w3 = (double)wsh[((k + 3) << 6) + c];
    #pragma unroll
    for (int i = 0; i < 4; ++i){
      const float4 xv = *(const float4*)&xs[(((w << 2) + i) << 7) + k];
      acc[i] = fma((double)xv.x, w0, acc[i]);
      acc[i] = fma((double)xv.y, w1, acc[i]);
      acc[i] = fma((double)xv.z, w2, acc[i]);
      acc[i] = fma((double)xv.w, w3, acc[i]);
    }
  }
  #pragma unroll
  for (int i = 0; i < 4; ++i)
    out[((r0 + (w << 2) + i) << 6) + c] = (float)acc[i];
}

// ---------------- edges ----------------
// Block = 4 rows of graph gb; each wave fully owns one row (no block sync).
// Phase 1: threefry bits for all 1024 j (index packed in low 10 bits),
//          fused per-lane max.
// Phase 2: b16' = 16th-largest LANE-MAX via u32 bitonic sort (lane-maxes are
//          a subset of all values, so b16' <= true b16 -> cut is conservative).
// Phase 3: compact ALL j with bits >= cut = bits(z(b16') - 1.001) (cap 128;
//          true top-16 provably included: score<=z+1, kth score >= kth z >= z16').
// Phase 4: exact f64 scoring of candidates (bit-identical formulas),
//          64-lane bitonic sort on exact u64 keys, top-16 out.
__global__ __launch_bounds__(256) void edges_v7(
    const float* __restrict__ out32, const float* __restrict__ temp,
    float* __restrict__ rows_out, float* __restrict__ cols_out){
  __shared__ double hid[4][64];         // 2 KB
  __shared__ unsigned int cl[4][128];   // 2 KB
  const int tid = threadIdx.x, wave = tid >> 6, lane = tid & 63;
  const int gb = blockIdx.x >> 8;
  const int i0 = (blockIdx.x & 255) << 2;
  const int r  = i0 + wave;
  const float* __restrict__ og = out32 + ((size_t)gb << 16);

  hid[wave][lane] = (double)og[((size_t)r << 6) + lane];

  const unsigned int base = ((unsigned int)gb << 20) | ((unsigned int)r << 10);

  // Phase 1: bits for j = m*64 + lane, with running per-lane max
  unsigned int v[16];
  unsigned int pmax = 0u;
  #pragma unroll
  for (int m = 0; m < 16; ++m){
    const unsigned int j = (unsigned int)(m << 6) + (unsigned int)lane;
    unsigned int bits = tf_bits_part(base | j);
    v[m] = (bits & ~1023u) | (1023u - j);   // low 10 bits don't feed u
    pmax = (v[m] > pmax) ? v[m] : pmax;
  }

  // Phase 2: 16th-largest lane-max (conservative surrogate for b16)
  unsigned int sorted = bitonic32_desc(pmax, lane);
  unsigned int b16p = __shfl(sorted, 15, 64);

  // conservative cut: keep j iff z_j >= z(b16') - 1.001  (score <= z + 1)
  float u16 = __uint_as_float(0x3f800000u | (b16p >> 9)) - 1.0f;
  float z16 = -__logf(-__logf(u16));
  float uc  = __expf(-__expf(-(z16 - 1.001f)));
  unsigned int cp = ((__float_as_uint(1.0f + uc) & 0x7FFFFFu) << 9) & ~1023u;

  // Phase 3: compaction of all survivors (>=16 guaranteed since cut < b16')
  int cnt = 0;
  #pragma unroll
  for (int m = 0; m < 16; ++m) cnt += (v[m] >= cp) ? 1 : 0;
  int s = cnt;
  #pragma unroll
  for (int off = 1; off < 64; off <<= 1){
    int o = __shfl_up(s, off, 64);
    s += (lane >= off) ? o : 0;
  }
  int nc = __shfl(s, 63, 64);
  nc = (nc > 128) ? 128 : nc;
  int slot = s - cnt;
  #pragma unroll
  for (int m = 0; m < 16; ++m){
    if (v[m] >= cp && slot < 128){
      cl[wave][slot] = 1023u - (v[m] & 1023u);
      ++slot;
    }
  }

  // Phase 4: exact scoring + sort
  const double Td = (double)temp[0];
  const bool act1 = (lane < nc);
  unsigned int jc1 = act1 ? cl[wave][lane] : 0u;
  unsigned long long key = score_cand(og, hid[wave], jc1, base, Td, act1);
  key = bitonic64_desc(key, lane);

  if (nc > 64){
    const int idx2 = 64 + lane;
    const bool act2 = (idx2 < nc);
    unsigned int jc2 = act2 ? cl[wave][idx2] : 0u;
    unsigned long long k2 = score_cand(og, hid[wave], jc2, base, Td, act2);
    k2 = bitonic64_desc(k2, lane);
    unsigned long long kr = __shfl(k2, 63 - lane, 64);
    key = (kr > key) ? kr : key;          // elementwise top-64 (bitonic)
    #pragma unroll
    for (int j = 32; j; j >>= 1){         // descending clean
      unsigned long long o = __shfl_xor(key, j, 64);
      bool left = (lane & j) == 0;
      bool take = left ? (o > key) : (o < key);
      key = take ? o : key;
    }
  }

  const int grow = (gb << 10) + r;
  if (lane < 16){
    rows_out[((size_t)grow << 4) + lane] = (float)grow;
    cols_out[((size_t)grow << 4) + lane] =
        (float)((gb << 10) + (1023 - (int)(key & 1023ull)));
  }
}

extern "C" void kernel_launch(void* const* d_in, const int* in_sizes, int n_in,
                              void* d_out, int out_size, void* d_ws, size_t ws_size,
                              hipStream_t stream){
  const float* x = (const float*)d_in[0];
  const float* W = (const float*)d_in[1];
  const float* b = (const float*)d_in[2];
  const float* T = (const float*)d_in[3];
  float* out      = (float*)d_out;
  float* rows_out = out + OUT_ELEMS;
  float* cols_out = rows_out + EDGE_ELEMS;

  encoder_v7<<<2048, 256, 0, stream>>>(x, W, b, out);
  edges_v7<<<8192, 256, 0, stream>>>(out, T, rows_out, cols_out);
}

// Round 11
// 211.364 us; speedup vs baseline: 3.6802x; 1.0167x over previous
//
#include <hip/hip_runtime.h>
#include <math.h>

// B=32 graphs, N=1024 nodes, D=128 in-dim, C=64 out-dim, K=16.
#define OUT_ELEMS 2097152   // 32768*64
#define EDGE_ELEMS 524288   // 32*1024*16

__device__ __forceinline__ unsigned int rotl32(unsigned int x, int r){
  return (x << r) | (x >> (32 - r));
}

// JAX partitionable threefry, key (0,1): counter = (0, e); out = o0 ^ o1.
__device__ __forceinline__ unsigned int tf_bits_part(unsigned int e){
  unsigned int x0 = 0u, x1 = e;
  const unsigned int ks1 = 1u;
  const unsigned int ks2 = 0x1BD11BDBu;
  x1 += ks1;
#define TFR(r) { x0 += x1; x1 = rotl32(x1, r); x1 ^= x0; }
  TFR(13) TFR(15) TFR(26) TFR(6)
  x0 += ks1; x1 += ks2 + 1u;
  TFR(17) TFR(29) TFR(16) TFR(24)
  x0 += ks2; x1 += 0u + 2u;
  TFR(13) TFR(15) TFR(26) TFR(6)
  x0 += 0u;  x1 += ks1 + 3u;
  TFR(17) TFR(29) TFR(16) TFR(24)
  x0 += ks1; x1 += ks2 + 4u;
  TFR(13) TFR(15) TFR(26) TFR(6)
  x0 += ks2; x1 += 0u + 5u;
#undef TFR
  return x0 ^ x1;
}

// hardware f64 reciprocal + 2 Newton steps: rel err ~1e-16.
__device__ __forceinline__ double rcp64(double x){
  double r;
  asm("v_rcp_f64 %0, %1" : "=v"(r) : "v"(x));
  double e = fma(-x, r, 1.0); r = fma(r, e, r);
  e = fma(-x, r, 1.0); r = fma(r, e, r);
  return r;
}

// fast e^x for x in [-740, ~1]; rel err ~2e-11 (deg-9).
__device__ __forceinline__ double fast_exp(double x){
  double fn = __builtin_rint(x * 1.4426950408889634);
  int n = (int)fn;
  double r = fma(fn, -0.6931471803691238, x);
  r = fma(fn, -1.9082149292705877e-10, r);
  double p = 2.7557319223985893e-06;
  p = fma(r, p, 2.4801587301587302e-05);
  p = fma(r, p, 1.9841269841269841e-04);
  p = fma(r, p, 1.3888888888888889e-03);
  p = fma(r, p, 8.3333333333333333e-03);
  p = fma(r, p, 4.1666666666666664e-02);
  p = fma(r, p, 1.6666666666666666e-01);
  p = fma(r, p, 0.5);
  p = fma(r, p, 1.0);
  p = fma(r, p, 1.0);
  double scale = __longlong_as_double(((long long)(n + 1023)) << 52);
  return p * scale;
}

// fast ln(x), normal positive x; atanh form; abs err ~2e-11.
__device__ __forceinline__ double fast_log(double x){
  long long bx = __double_as_longlong(x);
  long long e = (bx >> 52) - 1023;
  double m = __longlong_as_double((bx & 0xFFFFFFFFFFFFFll) |
                                  0x3FF0000000000000ll);
  int big = m > 1.4142135623730951;
  m = big ? 0.5 * m : m;
  e += big;
  double s = (m - 1.0) * rcp64(m + 1.0);
  double s2 = s * s;
  double p = fma(s2, 2.0/11.0, 2.0/9.0);
  p = fma(s2, p, 2.0/7.0);
  p = fma(s2, p, 2.0/5.0);
  p = fma(s2, p, 2.0/3.0);
  double lm = fma(s * s2, p, 2.0 * s);
  return fma((double)e, 0.6931471805599453, lm);
}

// Exact f64 score of candidate jc (register-lean: float4-chunked loads).
// Accumulation order q=0..63 sequential — bit-identical to v5/v6/v7.
__device__ __forceinline__ unsigned long long score_cand(
    const float* __restrict__ og, const double* __restrict__ hrow,
    unsigned int jc, unsigned int base, double Td, bool act){
  const float4* cp4 = (const float4*)(og + ((size_t)jc << 6));
  double acc = 0.0;
  #pragma unroll
  for (int ch = 0; ch < 16; ++ch){
    float4 cf = cp4[ch];
    double d0 = hrow[(ch << 2) + 0] - (double)cf.x;
    double d1 = hrow[(ch << 2) + 1] - (double)cf.y;
    double d2 = hrow[(ch << 2) + 2] - (double)cf.z;
    double d3 = hrow[(ch << 2) + 3] - (double)cf.w;
    acc = fma(d0, d0, acc);
    acc = fma(d1, d1, acc);
    acc = fma(d2, d2, acc);
    acc = fma(d3, d3, acc);
  }
  if (!act) return 0ull;
  double sgm = fast_exp(-Td * acc);
  unsigned int bits = tf_bits_part(base | jc);
  float f = __uint_as_float(0x3f800000u | (bits >> 9)) - 1.0f;
  double u = (f > 0.0f) ? (double)f : 1.1754943508222875e-38;
  double w = -fast_log(u);
  double z = -fast_log(w);
  double sc = sgm + z;
  unsigned long long kb = (unsigned long long)__double_as_longlong(sc);
  kb ^= (unsigned long long)(((long long)kb) >> 63) | 0x8000000000000000ull;
  return (kb & ~1023ull) | (unsigned long long)(1023u - jc);
}

// Full descending bitonic sort of u64 keys across 64 lanes.
__device__ __forceinline__ unsigned long long bitonic64_desc(
    unsigned long long key, int lane){
  #pragma unroll
  for (int k = 2; k <= 64; k <<= 1){
    #pragma unroll
    for (int j = k >> 1; j; j >>= 1){
      unsigned long long o = __shfl_xor(key, j, 64);
      bool keep_hi = ((lane & k) == 0) == ((lane & j) == 0);
      key = (keep_hi == (o > key)) ? o : key;
    }
  }
  return key;
}

// Full descending bitonic sort of u32 keys across 64 lanes.
__device__ __forceinline__ unsigned int bitonic32_desc(
    unsigned int key, int lane){
  #pragma unroll
  for (int k = 2; k <= 64; k <<= 1){
    #pragma unroll
    for (int j = k >> 1; j; j >>= 1){
      unsigned int o = __shfl_xor(key, j, 64);
      bool keep_hi = ((lane & k) == 0) == ((lane & j) == 0);
      key = (keep_hi == (o > key)) ? o : key;
    }
  }
  return key;
}

// ---------------- encoder ----------------
// Block = 32 rows (1024 blocks). 8 f64 accumulator chains per thread (2x the
// ILP of v6/v7 — the f64 chains are latency-bound, not W-path-bound).
// k-sequential f64 accumulation — bit-identical `out` vs all passing versions.
__global__ __launch_bounds__(256) void encoder_v8(
    const float* __restrict__ x, const float* __restrict__ W,
    const float* __restrict__ b, float* __restrict__ out){
  __shared__ float xs[4096];    // 32 rows x 128 = 16 KB
  const int tid = threadIdx.x;
  const int w = tid >> 6, c = tid & 63;
  const size_t r0 = (size_t)blockIdx.x << 5;
  const float4* xg4 = (const float4*)(x + (r0 << 7));
  float4* xs4 = (float4*)xs;
  #pragma unroll
  for (int s = 0; s < 4; ++s)
    xs4[tid + (s << 8)] = xg4[tid + (s << 8)];
  __syncthreads();

  double acc[8];
  const double bc = (double)b[c];
  #pragma unroll
  for (int i = 0; i < 8; ++i) acc[i] = bc;

  #pragma unroll 4
  for (int k = 0; k < 128; k += 4){
    const double w0 = (double)W[((k + 0) << 6) + c];
    const double w1 = (double)W[((k + 1) << 6) + c];
    const double w2 = (double)W[((k + 2) << 6) + c];
    const double w3 = (double)W[((k + 3) << 6) + c];
    #pragma unroll
    for (int i = 0; i < 8; ++i){
      const float4 xv = *(const float4*)&xs[(((w << 3) + i) << 7) + k];
      acc[i] = fma((double)xv.x, w0, acc[i]);
      acc[i] = fma((double)xv.y, w1, acc[i]);
      acc[i] = fma((double)xv.z, w2, acc[i]);
      acc[i] = fma((double)xv.w, w3, acc[i]);
    }
  }
  #pragma unroll
  for (int i = 0; i < 8; ++i)
    out[((r0 + (w << 3) + i) << 6) + c] = (float)acc[i];
}

// ---------------- edges ----------------
// Block = 4 rows of graph gb; each wave fully owns one row (no block sync).
// Phase 1: threefry bits for all 1024 j (index packed in low 10 bits),
//          fused per-lane max.
// Phase 2: b16' = 16th-largest LANE-MAX via u32 bitonic (b16' <= true b16).
// Phase 3: compact all j with bits >= cut = bits(z(b16') - 1.001) (cap 128;
//          true top-16 provably included: score<=z+1, kth score >= kth z).
// Phase 4: exact f64 scoring of candidates (bit-identical formulas),
//          64-lane bitonic sort on exact u64 keys, top-16 out.
__global__ __launch_bounds__(256) void edges_v8(
    const float* __restrict__ out32, const float* __restrict__ temp,
    float* __restrict__ rows_out, float* __restrict__ cols_out){
  __shared__ double hid[4][64];         // 2 KB
  __shared__ unsigned int cl[4][128];   // 2 KB
  const int tid = threadIdx.x, wave = tid >> 6, lane = tid & 63;
  const int gb = blockIdx.x >> 8;
  const int i0 = (blockIdx.x & 255) << 2;
  const int r  = i0 + wave;
  const float* __restrict__ og = out32 + ((size_t)gb << 16);

  hid[wave][lane] = (double)og[((size_t)r << 6) + lane];

  const unsigned int base = ((unsigned int)gb << 20) | ((unsigned int)r << 10);

  // Phase 1: bits for j = m*64 + lane, with running per-lane max
  unsigned int v[16];
  unsigned int pmax = 0u;
  #pragma unroll
  for (int m = 0; m < 16; ++m){
    const unsigned int j = (unsigned int)(m << 6) + (unsigned int)lane;
    unsigned int bits = tf_bits_part(base | j);
    v[m] = (bits & ~1023u) | (1023u - j);   // low 10 bits don't feed u
    pmax = (v[m] > pmax) ? v[m] : pmax;
  }

  // Phase 2: 16th-largest lane-max (conservative surrogate for b16)
  unsigned int sorted = bitonic32_desc(pmax, lane);
  unsigned int b16p = __shfl(sorted, 15, 64);

  // conservative cut: keep j iff z_j >= z(b16') - 1.001  (score <= z + 1)
  float u16 = __uint_as_float(0x3f800000u | (b16p >> 9)) - 1.0f;
  float z16 = -__logf(-__logf(u16));
  float uc  = __expf(-__expf(-(z16 - 1.001f)));
  unsigned int cp = ((__float_as_uint(1.0f + uc) & 0x7FFFFFu) << 9) & ~1023u;

  // Phase 3: compaction of all survivors (>=16 guaranteed since cut < b16')
  int cnt = 0;
  #pragma unroll
  for (int m = 0; m < 16; ++m) cnt += (v[m] >= cp) ? 1 : 0;
  int s = cnt;
  #pragma unroll
  for (int off = 1; off < 64; off <<= 1){
    int o = __shfl_up(s, off, 64);
    s += (lane >= off) ? o : 0;
  }
  int nc = __shfl(s, 63, 64);
  nc = (nc > 128) ? 128 : nc;
  int slot = s - cnt;
  #pragma unroll
  for (int m = 0; m < 16; ++m){
    if (v[m] >= cp && slot < 128){
      cl[wave][slot] = 1023u - (v[m] & 1023u);
      ++slot;
    }
  }

  // Phase 4: exact scoring + sort
  const double Td = (double)temp[0];
  const bool act1 = (lane < nc);
  unsigned int jc1 = act1 ? cl[wave][lane] : 0u;
  unsigned long long key = score_cand(og, hid[wave], jc1, base, Td, act1);
  key = bitonic64_desc(key, lane);

  if (nc > 64){
    const int idx2 = 64 + lane;
    const bool act2 = (idx2 < nc);
    unsigned int jc2 = act2 ? cl[wave][idx2] : 0u;
    unsigned long long k2 = score_cand(og, hid[wave], jc2, base, Td, act2);
    k2 = bitonic64_desc(k2, lane);
    unsigned long long kr = __shfl(k2, 63 - lane, 64);
    key = (kr > key) ? kr : key;          // elementwise top-64 (bitonic)
    #pragma unroll
    for (int j = 32; j; j >>= 1){         // descending clean
      unsigned long long o = __shfl_xor(key, j, 64);
      bool left = (lane & j) == 0;
      bool take = left ? (o > key) : (o < key);
      key = take ? o : key;
    }
  }

  const int grow = (gb << 10) + r;
  if (lane < 16){
    rows_out[((size_t)grow << 4) + lane] = (float)grow;
    cols_out[((size_t)grow << 4) + lane] =
        (float)((gb << 10) + (1023 - (int)(key & 1023ull)));
  }
}

extern "C" void kernel_launch(void* const* d_in, const int* in_sizes, int n_in,
                              void* d_out, int out_size, void* d_ws, size_t ws_size,
                              hipStream_t stream){
  const float* x = (const float*)d_in[0];
  const float* W = (const float*)d_in[1];
  const float* b = (const float*)d_in[2];
  const float* T = (const float*)d_in[3];
  float* out      = (float*)d_out;
  float* rows_out = out + OUT_ELEMS;
  float* cols_out = rows_out + EDGE_ELEMS;

  encoder_v8<<<1024, 256, 0, stream>>>(x, W, b, out);
  edges_v8<<<8192, 256, 0, stream>>>(out, T, rows_out, cols_out);
}

// Round 12
// 198.507 us; speedup vs baseline: 3.9186x; 1.0648x over previous
//
#include <hip/hip_runtime.h>
#include <math.h>

// B=32 graphs, N=1024 nodes, D=128 in-dim, C=64 out-dim, K=16.
#define OUT_ELEMS 2097152   // 32768*64
#define EDGE_ELEMS 524288   // 32*1024*16

__device__ __forceinline__ unsigned int rotl32(unsigned int x, int r){
  return (x << r) | (x >> (32 - r));
}

// JAX partitionable threefry, key (0,1): counter = (0, e); out = o0 ^ o1.
__device__ __forceinline__ unsigned int tf_bits_part(unsigned int e){
  unsigned int x0 = 0u, x1 = e;
  const unsigned int ks1 = 1u;
  const unsigned int ks2 = 0x1BD11BDBu;
  x1 += ks1;
#define TFR(r) { x0 += x1; x1 = rotl32(x1, r); x1 ^= x0; }
  TFR(13) TFR(15) TFR(26) TFR(6)
  x0 += ks1; x1 += ks2 + 1u;
  TFR(17) TFR(29) TFR(16) TFR(24)
  x0 += ks2; x1 += 0u + 2u;
  TFR(13) TFR(15) TFR(26) TFR(6)
  x0 += 0u;  x1 += ks1 + 3u;
  TFR(17) TFR(29) TFR(16) TFR(24)
  x0 += ks1; x1 += ks2 + 4u;
  TFR(13) TFR(15) TFR(26) TFR(6)
  x0 += ks2; x1 += 0u + 5u;
#undef TFR
  return x0 ^ x1;
}

// hardware f64 reciprocal + 2 Newton steps: rel err ~1e-16.
__device__ __forceinline__ double rcp64(double x){
  double r;
  asm("v_rcp_f64 %0, %1" : "=v"(r) : "v"(x));
  double e = fma(-x, r, 1.0); r = fma(r, e, r);
  e = fma(-x, r, 1.0); r = fma(r, e, r);
  return r;
}

// fast e^x for x in [-740, ~1]; rel err ~2e-11 (deg-9).
__device__ __forceinline__ double fast_exp(double x){
  double fn = __builtin_rint(x * 1.4426950408889634);
  int n = (int)fn;
  double r = fma(fn, -0.6931471803691238, x);
  r = fma(fn, -1.9082149292705877e-10, r);
  double p = 2.7557319223985893e-06;
  p = fma(r, p, 2.4801587301587302e-05);
  p = fma(r, p, 1.9841269841269841e-04);
  p = fma(r, p, 1.3888888888888889e-03);
  p = fma(r, p, 8.3333333333333333e-03);
  p = fma(r, p, 4.1666666666666664e-02);
  p = fma(r, p, 1.6666666666666666e-01);
  p = fma(r, p, 0.5);
  p = fma(r, p, 1.0);
  p = fma(r, p, 1.0);
  double scale = __longlong_as_double(((long long)(n + 1023)) << 52);
  return p * scale;
}

// fast ln(x), normal positive x; atanh form; abs err ~2e-11.
__device__ __forceinline__ double fast_log(double x){
  long long bx = __double_as_longlong(x);
  long long e = (bx >> 52) - 1023;
  double m = __longlong_as_double((bx & 0xFFFFFFFFFFFFFll) |
                                  0x3FF0000000000000ll);
  int big = m > 1.4142135623730951;
  m = big ? 0.5 * m : m;
  e += big;
  double s = (m - 1.0) * rcp64(m + 1.0);
  double s2 = s * s;
  double p = fma(s2, 2.0/11.0, 2.0/9.0);
  p = fma(s2, p, 2.0/7.0);
  p = fma(s2, p, 2.0/5.0);
  p = fma(s2, p, 2.0/3.0);
  double lm = fma(s * s2, p, 2.0 * s);
  return fma((double)e, 0.6931471805599453, lm);
}

// Exact f64 score of candidate jc. Accumulation order q=0..63 sequential —
// bit-identical to v5..v8. unroll 4: only 4 float4 loads in flight (VGPR cap).
__device__ __forceinline__ unsigned long long score_cand(
    const float* __restrict__ og, const double* __restrict__ hrow,
    unsigned int jc, unsigned int base, double Td, bool act){
  const float4* cp4 = (const float4*)(og + ((size_t)jc << 6));
  double acc = 0.0;
  #pragma unroll 4
  for (int ch = 0; ch < 16; ++ch){
    float4 cf = cp4[ch];
    double d0 = hrow[(ch << 2) + 0] - (double)cf.x;
    double d1 = hrow[(ch << 2) + 1] - (double)cf.y;
    double d2 = hrow[(ch << 2) + 2] - (double)cf.z;
    double d3 = hrow[(ch << 2) + 3] - (double)cf.w;
    acc = fma(d0, d0, acc);
    acc = fma(d1, d1, acc);
    acc = fma(d2, d2, acc);
    acc = fma(d3, d3, acc);
  }
  if (!act) return 0ull;
  double sgm = fast_exp(-Td * acc);
  unsigned int bits = tf_bits_part(base | jc);
  float f = __uint_as_float(0x3f800000u | (bits >> 9)) - 1.0f;
  double u = (f > 0.0f) ? (double)f : 1.1754943508222875e-38;
  double w = -fast_log(u);
  double z = -fast_log(w);
  double sc = sgm + z;
  unsigned long long kb = (unsigned long long)__double_as_longlong(sc);
  kb ^= (unsigned long long)(((long long)kb) >> 63) | 0x8000000000000000ull;
  return (kb & ~1023ull) | (unsigned long long)(1023u - jc);
}

// Full descending bitonic sort of u64 keys across 64 lanes.
__device__ __forceinline__ unsigned long long bitonic64_desc(
    unsigned long long key, int lane){
  #pragma unroll
  for (int k = 2; k <= 64; k <<= 1){
    #pragma unroll
    for (int j = k >> 1; j; j >>= 1){
      unsigned long long o = __shfl_xor(key, j, 64);
      bool keep_hi = ((lane & k) == 0) == ((lane & j) == 0);
      key = (keep_hi == (o > key)) ? o : key;
    }
  }
  return key;
}

// Full descending bitonic sort of u32 keys across 64 lanes.
__device__ __forceinline__ unsigned int bitonic32_desc(
    unsigned int key, int lane){
  #pragma unroll
  for (int k = 2; k <= 64; k <<= 1){
    #pragma unroll
    for (int j = k >> 1; j; j >>= 1){
      unsigned int o = __shfl_xor(key, j, 64);
      bool keep_hi = ((lane & k) == 0) == ((lane & j) == 0);
      key = (keep_hi == (o > key)) ? o : key;
    }
  }
  return key;
}

// ---------------- encoder ----------------
// v4's proven compute core: 512 blocks x 64 rows, 16 f64 chains/thread,
// x tile + W tile in LDS (64 KB -> 2 blocks/CU, fully resident grid).
// k-sequential f64 accumulation — bit-identical `out` vs all passing versions.
__global__ __launch_bounds__(256) void encoder_v9(
    const float* __restrict__ x, const float* __restrict__ W,
    const float* __restrict__ b, float* __restrict__ out){
  __shared__ float xs[8192];   // 64 rows x 128
  __shared__ float wsh[8192];  // 128 x 64
  const int tid = threadIdx.x;
  const int w = tid >> 6, c = tid & 63;
  const size_t r0 = (size_t)blockIdx.x << 6;

  { // stage x tile + W (coalesced float4)
    const float4* xg4 = (const float4*)(x + (r0 << 7));
    const float4* wg4 = (const float4*)W;
    float4* xs4 = (float4*)xs;
    float4* ws4 = (float4*)wsh;
    #pragma unroll
    for (int s = 0; s < 8; ++s){
      xs4[tid + (s << 8)] = xg4[tid + (s << 8)];
      ws4[tid + (s << 8)] = wg4[tid + (s << 8)];
    }
  }
  __syncthreads();

  // wave w computes rows w*16..w*16+15, column c (f64, k-sequential)
  double acc[16];
  const double bc = (double)b[c];
  #pragma unroll
  for (int i = 0; i < 16; ++i) acc[i] = bc;

  #pragma unroll 4
  for (int k = 0; k < 128; k += 4){
    const double w0 = (double)wsh[((k + 0) << 6) + c];
    const double w1 = (double)wsh[((k + 1) << 6) + c];
    const double w2 = (double)wsh[((k + 2) << 6) + c];
    const double w3 = (double)wsh[((k + 3) << 6) + c];
    #pragma unroll
    for (int i = 0; i < 16; ++i){
      const float4 xv = *(const float4*)&xs[(((w << 4) + i) << 7) + k];
      acc[i] = fma((double)xv.x, w0, acc[i]);
      acc[i] = fma((double)xv.y, w1, acc[i]);
      acc[i] = fma((double)xv.z, w2, acc[i]);
      acc[i] = fma((double)xv.w, w3, acc[i]);
    }
  }
  #pragma unroll
  for (int i = 0; i < 16; ++i)
    out[((r0 + (w << 4) + i) << 6) + c] = (float)acc[i];
}

// ---------------- edges ----------------
// Block = 4 rows of graph gb; each wave fully owns one row (no block sync).
// Phase 1: threefry bits for all 1024 j (index packed in low 10 bits),
//          fused per-lane max.
// Phase 2: b16' = 16th-largest LANE-MAX via u32 bitonic (b16' <= true b16).
// Phase 3: compact all j with bits >= cut = bits(z(b16') - 1.001) (cap 128;
//          true top-16 provably included: score<=z+1, kth score >= kth z).
// Phase 4: exact f64 scoring of candidates (bit-identical formulas),
//          64-lane bitonic sort on exact u64 keys, top-16 out.
// launch_bounds (256,8): cap 64 VGPR -> 8 waves/SIMD.
__global__ __launch_bounds__(256, 8) void edges_v9(
    const float* __restrict__ out32, const float* __restrict__ temp,
    float* __restrict__ rows_out, float* __restrict__ cols_out){
  __shared__ double hid[4][64];         // 2 KB
  __shared__ unsigned int cl[4][128];   // 2 KB
  const int tid = threadIdx.x, wave = tid >> 6, lane = tid & 63;
  const int gb = blockIdx.x >> 8;
  const int i0 = (blockIdx.x & 255) << 2;
  const int r  = i0 + wave;
  const float* __restrict__ og = out32 + ((size_t)gb << 16);

  hid[wave][lane] = (double)og[((size_t)r << 6) + lane];

  const unsigned int base = ((unsigned int)gb << 20) | ((unsigned int)r << 10);

  // Phase 1: bits for j = m*64 + lane, with running per-lane max
  unsigned int v[16];
  unsigned int pmax = 0u;
  #pragma unroll
  for (int m = 0; m < 16; ++m){
    const unsigned int j = (unsigned int)(m << 6) + (unsigned int)lane;
    unsigned int bits = tf_bits_part(base | j);
    v[m] = (bits & ~1023u) | (1023u - j);   // low 10 bits don't feed u
    pmax = (v[m] > pmax) ? v[m] : pmax;
  }

  // Phase 2: 16th-largest lane-max (conservative surrogate for b16)
  unsigned int sorted = bitonic32_desc(pmax, lane);
  unsigned int b16p = __shfl(sorted, 15, 64);

  // conservative cut: keep j iff z_j >= z(b16') - 1.001  (score <= z + 1)
  float u16 = __uint_as_float(0x3f800000u | (b16p >> 9)) - 1.0f;
  float z16 = -__logf(-__logf(u16));
  float uc  = __expf(-__expf(-(z16 - 1.001f)));
  unsigned int cp = ((__float_as_uint(1.0f + uc) & 0x7FFFFFu) << 9) & ~1023u;

  // Phase 3: compaction of all survivors (>=16 guaranteed since cut < b16')
  int cnt = 0;
  #pragma unroll
  for (int m = 0; m < 16; ++m) cnt += (v[m] >= cp) ? 1 : 0;
  int s = cnt;
  #pragma unroll
  for (int off = 1; off < 64; off <<= 1){
    int o = __shfl_up(s, off, 64);
    s += (lane >= off) ? o : 0;
  }
  int nc = __shfl(s, 63, 64);
  nc = (nc > 128) ? 128 : nc;
  int slot = s - cnt;
  #pragma unroll
  for (int m = 0; m < 16; ++m){
    if (v[m] >= cp && slot < 128){
      cl[wave][slot] = 1023u - (v[m] & 1023u);
      ++slot;
    }
  }

  // Phase 4: exact scoring + sort
  const double Td = (double)temp[0];
  const bool act1 = (lane < nc);
  unsigned int jc1 = act1 ? cl[wave][lane] : 0u;
  unsigned long long key = score_cand(og, hid[wave], jc1, base, Td, act1);
  key = bitonic64_desc(key, lane);

  if (nc > 64){
    const int idx2 = 64 + lane;
    const bool act2 = (idx2 < nc);
    unsigned int jc2 = act2 ? cl[wave][idx2] : 0u;
    unsigned long long k2 = score_cand(og, hid[wave], jc2, base, Td, act2);
    k2 = bitonic64_desc(k2, lane);
    unsigned long long kr = __shfl(k2, 63 - lane, 64);
    key = (kr > key) ? kr : key;          // elementwise top-64 (bitonic)
    #pragma unroll
    for (int j = 32; j; j >>= 1){         // descending clean
      unsigned long long o = __shfl_xor(key, j, 64);
      bool left = (lane & j) == 0;
      bool take = left ? (o > key) : (o < key);
      key = take ? o : key;
    }
  }

  const int grow = (gb << 10) + r;
  if (lane < 16){
    rows_out[((size_t)grow << 4) + lane] = (float)grow;
    cols_out[((size_t)grow << 4) + lane] =
        (float)((gb << 10) + (1023 - (int)(key & 1023ull)));
  }
}

extern "C" void kernel_launch(void* const* d_in, const int* in_sizes, int n_in,
                              void* d_out, int out_size, void* d_ws, size_t ws_size,
                              hipStream_t stream){
  const float* x = (const float*)d_in[0];
  const float* W = (const float*)d_in[1];
  const float* b = (const float*)d_in[2];
  const float* T = (const float*)d_in[3];
  float* out      = (float*)d_out;
  float* rows_out = out + OUT_ELEMS;
  float* cols_out = rows_out + EDGE_ELEMS;

  encoder_v9<<<512, 256, 0, stream>>>(x, W, b, out);
  edges_v9<<<8192, 256, 0, stream>>>(out, T, rows_out, cols_out);
}

// Round 13
// 194.874 us; speedup vs baseline: 3.9916x; 1.0186x over previous
//
#include <hip/hip_runtime.h>
#include <math.h>

// B=32 graphs, N=1024 nodes, D=128 in-dim, C=64 out-dim, K=16.
#define OUT_ELEMS 2097152   // 32768*64
#define EDGE_ELEMS 524288   // 32*1024*16

__device__ __forceinline__ unsigned int rotl32(unsigned int x, int r){
  return (x << r) | (x >> (32 - r));
}

// JAX partitionable threefry, key (0,1): counter = (0, e); out = o0 ^ o1.
__device__ __forceinline__ unsigned int tf_bits_part(unsigned int e){
  unsigned int x0 = 0u, x1 = e;
  const unsigned int ks1 = 1u;
  const unsigned int ks2 = 0x1BD11BDBu;
  x1 += ks1;
#define TFR(r) { x0 += x1; x1 = rotl32(x1, r); x1 ^= x0; }
  TFR(13) TFR(15) TFR(26) TFR(6)
  x0 += ks1; x1 += ks2 + 1u;
  TFR(17) TFR(29) TFR(16) TFR(24)
  x0 += ks2; x1 += 0u + 2u;
  TFR(13) TFR(15) TFR(26) TFR(6)
  x0 += 0u;  x1 += ks1 + 3u;
  TFR(17) TFR(29) TFR(16) TFR(24)
  x0 += ks1; x1 += ks2 + 4u;
  TFR(13) TFR(15) TFR(26) TFR(6)
  x0 += ks2; x1 += 0u + 5u;
#undef TFR
  return x0 ^ x1;
}

// hardware f64 reciprocal + 2 Newton steps: rel err ~1e-16.
__device__ __forceinline__ double rcp64(double x){
  double r;
  asm("v_rcp_f64 %0, %1" : "=v"(r) : "v"(x));
  double e = fma(-x, r, 1.0); r = fma(r, e, r);
  e = fma(-x, r, 1.0); r = fma(r, e, r);
  return r;
}

// fast e^x for x in [-740, ~1]; rel err ~2e-11 (deg-9).
__device__ __forceinline__ double fast_exp(double x){
  double fn = __builtin_rint(x * 1.4426950408889634);
  int n = (int)fn;
  double r = fma(fn, -0.6931471803691238, x);
  r = fma(fn, -1.9082149292705877e-10, r);
  double p = 2.7557319223985893e-06;
  p = fma(r, p, 2.4801587301587302e-05);
  p = fma(r, p, 1.9841269841269841e-04);
  p = fma(r, p, 1.3888888888888889e-03);
  p = fma(r, p, 8.3333333333333333e-03);
  p = fma(r, p, 4.1666666666666664e-02);
  p = fma(r, p, 1.6666666666666666e-01);
  p = fma(r, p, 0.5);
  p = fma(r, p, 1.0);
  p = fma(r, p, 1.0);
  double scale = __longlong_as_double(((long long)(n + 1023)) << 52);
  return p * scale;
}

// fast ln(x), normal positive x; atanh form; abs err ~2e-11.
__device__ __forceinline__ double fast_log(double x){
  long long bx = __double_as_longlong(x);
  long long e = (bx >> 52) - 1023;
  double m = __longlong_as_double((bx & 0xFFFFFFFFFFFFFll) |
                                  0x3FF0000000000000ll);
  int big = m > 1.4142135623730951;
  m = big ? 0.5 * m : m;
  e += big;
  double s = (m - 1.0) * rcp64(m + 1.0);
  double s2 = s * s;
  double p = fma(s2, 2.0/11.0, 2.0/9.0);
  p = fma(s2, p, 2.0/7.0);
  p = fma(s2, p, 2.0/5.0);
  p = fma(s2, p, 2.0/3.0);
  double lm = fma(s * s2, p, 2.0 * s);
  return fma((double)e, 0.6931471805599453, lm);
}

// Exact f64 score of candidate jc. Accumulation order q=0..63 sequential —
// bit-identical to v5..v9. unroll 4: only 4 float4 loads in flight.
__device__ __forceinline__ unsigned long long score_cand(
    const float* __restrict__ og, const double* __restrict__ hrow,
    unsigned int jc, unsigned int base, double Td, bool act){
  const float4* cp4 = (const float4*)(og + ((size_t)jc << 6));
  double acc = 0.0;
  #pragma unroll 4
  for (int ch = 0; ch < 16; ++ch){
    float4 cf = cp4[ch];
    double d0 = hrow[(ch << 2) + 0] - (double)cf.x;
    double d1 = hrow[(ch << 2) + 1] - (double)cf.y;
    double d2 = hrow[(ch << 2) + 2] - (double)cf.z;
    double d3 = hrow[(ch << 2) + 3] - (double)cf.w;
    acc = fma(d0, d0, acc);
    acc = fma(d1, d1, acc);
    acc = fma(d2, d2, acc);
    acc = fma(d3, d3, acc);
  }
  if (!act) return 0ull;
  double sgm = fast_exp(-Td * acc);
  unsigned int bits = tf_bits_part(base | jc);
  float f = __uint_as_float(0x3f800000u | (bits >> 9)) - 1.0f;
  double u = (f > 0.0f) ? (double)f : 1.1754943508222875e-38;
  double w = -fast_log(u);
  double z = -fast_log(w);
  double sc = sgm + z;
  unsigned long long kb = (unsigned long long)__double_as_longlong(sc);
  kb ^= (unsigned long long)(((long long)kb) >> 63) | 0x8000000000000000ull;
  return (kb & ~1023ull) | (unsigned long long)(1023u - jc);
}

// Full descending bitonic sort of u64 keys across 64 lanes.
__device__ __forceinline__ unsigned long long bitonic64_desc(
    unsigned long long key, int lane){
  #pragma unroll
  for (int k = 2; k <= 64; k <<= 1){
    #pragma unroll
    for (int j = k >> 1; j; j >>= 1){
      unsigned long long o = __shfl_xor(key, j, 64);
      bool keep_hi = ((lane & k) == 0) == ((lane & j) == 0);
      key = (keep_hi == (o > key)) ? o : key;
    }
  }
  return key;
}

// Full descending bitonic sort of u32 keys across 64 lanes.
__device__ __forceinline__ unsigned int bitonic32_desc(
    unsigned int key, int lane){
  #pragma unroll
  for (int k = 2; k <= 64; k <<= 1){
    #pragma unroll
    for (int j = k >> 1; j; j >>= 1){
      unsigned int o = __shfl_xor(key, j, 64);
      bool keep_hi = ((lane & k) == 0) == ((lane & j) == 0);
      key = (keep_hi == (o > key)) ? o : key;
    }
  }
  return key;
}

// ---------------- encoder ----------------
// 512 blocks x 64 rows, 16 f64 chains/thread. x tile converted to f64 ONCE
// at staging (v_cvt_f64_f32 is exact -> same f64 values, same FMA order ->
// bit-identical out). Kills the 64 cvt/k-group that doubled f64-pipe issue.
// W (32 KB, L1-resident) read from global with only 4 cvts/k-group.
__global__ __launch_bounds__(256) void encoder_v10(
    const float* __restrict__ x, const float* __restrict__ W,
    const float* __restrict__ b, float* __restrict__ out){
  __shared__ double xs64[8192];   // 64 rows x 128 f64 = 64 KB
  const int tid = threadIdx.x;
  const int w = tid >> 6, c = tid & 63;
  const size_t r0 = (size_t)blockIdx.x << 6;

  { // stage x tile, converting f32 -> f64 (exact) once
    const float4* xg4 = (const float4*)(x + (r0 << 7));
    #pragma unroll
    for (int s = 0; s < 8; ++s){
      const int idx = tid + (s << 8);
      float4 v = xg4[idx];
      double2 d0, d1;
      d0.x = (double)v.x; d0.y = (double)v.y;
      d1.x = (double)v.z; d1.y = (double)v.w;
      *(double2*)&xs64[(idx << 2) + 0] = d0;
      *(double2*)&xs64[(idx << 2) + 2] = d1;
    }
  }
  __syncthreads();

  // wave w computes rows w*16..w*16+15, column c (f64, k-sequential)
  double acc[16];
  const double bc = (double)b[c];
  #pragma unroll
  for (int i = 0; i < 16; ++i) acc[i] = bc;

  #pragma unroll 4
  for (int k = 0; k < 128; k += 4){
    const double w0 = (double)W[((k + 0) << 6) + c];
    const double w1 = (double)W[((k + 1) << 6) + c];
    const double w2 = (double)W[((k + 2) << 6) + c];
    const double w3 = (double)W[((k + 3) << 6) + c];
    #pragma unroll
    for (int i = 0; i < 16; ++i){
      const double2 xa = *(const double2*)&xs64[(((w << 4) + i) << 7) + k];
      const double2 xb = *(const double2*)&xs64[(((w << 4) + i) << 7) + k + 2];
      acc[i] = fma(xa.x, w0, acc[i]);
      acc[i] = fma(xa.y, w1, acc[i]);
      acc[i] = fma(xb.x, w2, acc[i]);
      acc[i] = fma(xb.y, w3, acc[i]);
    }
  }
  #pragma unroll
  for (int i = 0; i < 16; ++i)
    out[((r0 + (w << 4) + i) << 6) + c] = (float)acc[i];
}

// ---------------- edges ----------------
// Unchanged from v9 (proven: 125 us, VGPR 28, occupancy 73%).
__global__ __launch_bounds__(256, 8) void edges_v10(
    const float* __restrict__ out32, const float* __restrict__ temp,
    float* __restrict__ rows_out, float* __restrict__ cols_out){
  __shared__ double hid[4][64];         // 2 KB
  __shared__ unsigned int cl[4][128];   // 2 KB
  const int tid = threadIdx.x, wave = tid >> 6, lane = tid & 63;
  const int gb = blockIdx.x >> 8;
  const int i0 = (blockIdx.x & 255) << 2;
  const int r  = i0 + wave;
  const float* __restrict__ og = out32 + ((size_t)gb << 16);

  hid[wave][lane] = (double)og[((size_t)r << 6) + lane];

  const unsigned int base = ((unsigned int)gb << 20) | ((unsigned int)r << 10);

  // Phase 1: bits for j = m*64 + lane, with running per-lane max
  unsigned int v[16];
  unsigned int pmax = 0u;
  #pragma unroll
  for (int m = 0; m < 16; ++m){
    const unsigned int j = (unsigned int)(m << 6) + (unsigned int)lane;
    unsigned int bits = tf_bits_part(base | j);
    v[m] = (bits & ~1023u) | (1023u - j);   // low 10 bits don't feed u
    pmax = (v[m] > pmax) ? v[m] : pmax;
  }

  // Phase 2: 16th-largest lane-max (conservative surrogate for b16)
  unsigned int sorted = bitonic32_desc(pmax, lane);
  unsigned int b16p = __shfl(sorted, 15, 64);

  // conservative cut: keep j iff z_j >= z(b16') - 1.001  (score <= z + 1)
  float u16 = __uint_as_float(0x3f800000u | (b16p >> 9)) - 1.0f;
  float z16 = -__logf(-__logf(u16));
  float uc  = __expf(-__expf(-(z16 - 1.001f)));
  unsigned int cp = ((__float_as_uint(1.0f + uc) & 0x7FFFFFu) << 9) & ~1023u;

  // Phase 3: compaction of all survivors (>=16 guaranteed since cut < b16')
  int cnt = 0;
  #pragma unroll
  for (int m = 0; m < 16; ++m) cnt += (v[m] >= cp) ? 1 : 0;
  int s = cnt;
  #pragma unroll
  for (int off = 1; off < 64; off <<= 1){
    int o = __shfl_up(s, off, 64);
    s += (lane >= off) ? o : 0;
  }
  int nc = __shfl(s, 63, 64);
  nc = (nc > 128) ? 128 : nc;
  int slot = s - cnt;
  #pragma unroll
  for (int m = 0; m < 16; ++m){
    if (v[m] >= cp && slot < 128){
      cl[wave][slot] = 1023u - (v[m] & 1023u);
      ++slot;
    }
  }

  // Phase 4: exact scoring + sort
  const double Td = (double)temp[0];
  const bool act1 = (lane < nc);
  unsigned int jc1 = act1 ? cl[wave][lane] : 0u;
  unsigned long long key = score_cand(og, hid[wave], jc1, base, Td, act1);
  key = bitonic64_desc(key, lane);

  if (nc > 64){
    const int idx2 = 64 + lane;
    const bool act2 = (idx2 < nc);
    unsigned int jc2 = act2 ? cl[wave][idx2] : 0u;
    unsigned long long k2 = score_cand(og, hid[wave], jc2, base, Td, act2);
    k2 = bitonic64_desc(k2, lane);
    unsigned long long kr = __shfl(k2, 63 - lane, 64);
    key = (kr > key) ? kr : key;          // elementwise top-64 (bitonic)
    #pragma unroll
    for (int j = 32; j; j >>= 1){         // descending clean
      unsigned long long o = __shfl_xor(key, j, 64);
      bool left = (lane & j) == 0;
      bool take = left ? (o > key) : (o < key);
      key = take ? o : key;
    }
  }

  const int grow = (gb << 10) + r;
  if (lane < 16){
    rows_out[((size_t)grow << 4) + lane] = (float)grow;
    cols_out[((size_t)grow << 4) + lane] =
        (float)((gb << 10) + (1023 - (int)(key & 1023ull)));
  }
}

extern "C" void kernel_launch(void* const* d_in, const int* in_sizes, int n_in,
                              void* d_out, int out_size, void* d_ws, size_t ws_size,
                              hipStream_t stream){
  const float* x = (const float*)d_in[0];
  const float* W = (const float*)d_in[1];
  const float* b = (const float*)d_in[2];
  const float* T = (const float*)d_in[3];
  float* out      = (float*)d_out;
  float* rows_out = out + OUT_ELEMS;
  float* cols_out = rows_out + EDGE_ELEMS;

  encoder_v10<<<512, 256, 0, stream>>>(x, W, b, out);
  edges_v10<<<8192, 256, 0, stream>>>(out, T, rows_out, cols_out);
}